// Round 5
// baseline (347.345 us; speedup 1.0000x reference)
//
#include <hip/hip_runtime.h>
#include <stdint.h>

#define N_NODES 100000
#define N_EDGES 1600000
#define NFEAT 256
#define NHID 64
#define N_ELEMS (N_NODES * NHID)   // 6,400,000

// R11: row-buckets of 128 rows; per-bucket LDS counting sort.
#define BSHIFT 7
#define NBUCK 782                  // ceil(100000/128)
#define CHUNK 4096                 // edges per bhist/bucket block
#define NBBLK ((N_EDGES + CHUNK - 1) / CHUNK)   // 391
#define CAP 2560                   // stage capacity; mean 2048, sigma ~45 -> +11s

// R13/R14 gather: block = 52 contiguous nodes, metadata staged in LDS.
#define NPB 52                     // nodes per block
#define GBLK ((N_NODES + NPB - 1) / NPB)        // 1924
#define ECAP 1536                  // LDS edge records; mean 832, sigma 29 -> +24s
#define GDEPTH 16                  // in-flight gathers per wave

// Config (validated R6/R7): inputs f32, output f32, dropout = JAX partitionable
// threefry (key=(0,42), counter (0,i), bits = o0^o1).
//
// R13 post-mortem: LDS metadata alone didn't help (84us). VGPR_Count=28 ->
//   compiler recycled registers, forcing vmcnt drains between gathers (real
//   pipeline depth ~2, not 8); and the scalar tail loop (avg ~4 edges/node,
//   mean degree 16) paid full ~700cy latency per edge.
// R14: __launch_bounds__(256,4) raises VGPR budget to 128 (occupancy floor
//   = measured 50%, no TLP loss). Inner loop = fixed 16-deep fully-unrolled
//   predicated chunks: clamped LDS index + zeroed weight for OOB -> no scalar
//   tail, 16 independent gathers in flight always. OOB dups hit the same
//   line (L2). 16/wave x 4 waves/SIMD = 64 loads in flight per SIMD.
//
// ws layout:
//   sums[128] f32 | hb[1024] i32 | scaleshift[128] f32 | bbase[1024] i32
//   | bcur[1024] i32 | rowptr[100004] i32 | wt[16384] ushort
//   | agg[6.4M] f32 | sorted[1.6M] int2
// support[6.4M] bf16 staged in d_out (dead before apply overwrites).
// bucketed[1.6M] int2 aliases agg (dead until gather writes agg).

typedef __attribute__((ext_vector_type(8))) short bf16x8;
typedef __attribute__((ext_vector_type(4))) float f32x4;

__device__ __forceinline__ unsigned short f2bf(float f) {
    uint32_t u = __float_as_uint(f);
    u += 0x7FFFu + ((u >> 16) & 1u);   // RNE
    return (unsigned short)(u >> 16);
}
__device__ __forceinline__ float bf2f(unsigned short u) {
    return __uint_as_float(((uint32_t)u) << 16);
}

// ---------------------------------------------------------------------------
// W^T prep: wt[n][k] = bf16(W[k][n])
// ---------------------------------------------------------------------------
__global__ __launch_bounds__(256) void wtprep_kernel(const float* __restrict__ W,
                                                     unsigned short* __restrict__ wt) {
    int i = blockIdx.x * 256 + threadIdx.x;
    if (i < NFEAT * NHID) {
        int k = i >> 6, n = i & 63;
        wt[n * NFEAT + k] = f2bf(W[i]);
    }
}

// ---------------------------------------------------------------------------
// GEMM (MFMA bf16): support[N x 64] = x[N x 256] @ W[256 x 64], bf16 out.
// ---------------------------------------------------------------------------
__global__ __launch_bounds__(256) void gemm_kernel(const float* __restrict__ x,
                                                   const unsigned short* __restrict__ wt,
                                                   unsigned short* __restrict__ support) {
    __shared__ unsigned short Abf[64][264];  // row stride 528B, 16B-aligned
    __shared__ unsigned short Bt[64][264];   // Bt[n][k]
    const int t = threadIdx.x;
    const int row0 = blockIdx.x * 64;

    {
        const int r = t >> 6;
        const int c4 = t & 63;
        #pragma unroll
        for (int rr = 0; rr < 16; rr++) {
            int lr_ = rr * 4 + r;
            int gr = row0 + lr_;
            float4 v = make_float4(0.f, 0.f, 0.f, 0.f);
            if (gr < N_NODES) v = *(const float4*)&x[(size_t)gr * NFEAT + c4 * 4];
            ushort4 u;
            u.x = f2bf(v.x); u.y = f2bf(v.y); u.z = f2bf(v.z); u.w = f2bf(v.w);
            *(ushort4*)&Abf[lr_][c4 * 4] = u;
        }
    }
    {
        const int rB = t >> 5;
        const int ch = t & 31;
        #pragma unroll
        for (int rr = 0; rr < 8; rr++) {
            int n = rr * 8 + rB;
            uint4 v = *(const uint4*)&wt[n * NFEAT + ch * 8];
            *(uint4*)&Bt[n][ch * 8] = v;
        }
    }
    __syncthreads();

    const int lane = t & 63;
    const int w = t >> 6;
    const int m = lane & 15;
    const int q = lane >> 4;
    f32x4 acc0 = {0.f, 0.f, 0.f, 0.f};
    f32x4 acc1 = acc0, acc2 = acc0, acc3 = acc0;

    #pragma unroll
    for (int ks = 0; ks < NFEAT; ks += 32) {
        bf16x8 af = *(const bf16x8*)&Abf[w * 16 + m][ks + q * 8];
        bf16x8 b0 = *(const bf16x8*)&Bt[ 0 + m][ks + q * 8];
        bf16x8 b1 = *(const bf16x8*)&Bt[16 + m][ks + q * 8];
        bf16x8 b2 = *(const bf16x8*)&Bt[32 + m][ks + q * 8];
        bf16x8 b3 = *(const bf16x8*)&Bt[48 + m][ks + q * 8];
        acc0 = __builtin_amdgcn_mfma_f32_16x16x32_bf16(af, b0, acc0, 0, 0, 0);
        acc1 = __builtin_amdgcn_mfma_f32_16x16x32_bf16(af, b1, acc1, 0, 0, 0);
        acc2 = __builtin_amdgcn_mfma_f32_16x16x32_bf16(af, b2, acc2, 0, 0, 0);
        acc3 = __builtin_amdgcn_mfma_f32_16x16x32_bf16(af, b3, acc3, 0, 0, 0);
    }

    // C/D layout: row = q*4 + reg, col = nt*16 + m
    #pragma unroll
    for (int reg = 0; reg < 4; reg++) {
        int grow = row0 + w * 16 + q * 4 + reg;
        if (grow < N_NODES) {
            support[(size_t)grow * NHID +  0 + m] = f2bf(acc0[reg]);
            support[(size_t)grow * NHID + 16 + m] = f2bf(acc1[reg]);
            support[(size_t)grow * NHID + 32 + m] = f2bf(acc2[reg]);
            support[(size_t)grow * NHID + 48 + m] = f2bf(acc3[reg]);
        }
    }
}

// ---------------------------------------------------------------------------
// Bucket-level histogram (LDS-aggregated).
// ---------------------------------------------------------------------------
__global__ __launch_bounds__(256) void bhist_kernel(const int* __restrict__ row,
                                                    int* __restrict__ hb) {
    __shared__ int lcnt[NBUCK];
    const int t = threadIdx.x;
    for (int b = t; b < NBUCK; b += 256) lcnt[b] = 0;
    __syncthreads();
    const int e0 = blockIdx.x * CHUNK;
    #pragma unroll
    for (int i = 0; i < 16; i++) {
        int e = e0 + i * 256 + t;
        if (e < N_EDGES) atomicAdd(&lcnt[row[e] >> BSHIFT], 1);
    }
    __syncthreads();
    for (int b = t; b < NBUCK; b += 256) {
        int c = lcnt[b];
        if (c) atomicAdd(&hb[b], c);
    }
}

// ---------------------------------------------------------------------------
// Exclusive scan of bucket counts -> bucket bases; seed bucket cursors.
// ---------------------------------------------------------------------------
__global__ __launch_bounds__(1024) void bscan_kernel(const int* __restrict__ hb,
                                                     int* __restrict__ bbase,
                                                     int* __restrict__ bcur,
                                                     int* __restrict__ rowptr) {
    __shared__ int s[1024];
    const int t = threadIdx.x;
    int v = (t < NBUCK) ? hb[t] : 0;
    s[t] = v;
    __syncthreads();
    #pragma unroll
    for (int off = 1; off < 1024; off <<= 1) {
        int u = (t >= off) ? s[t - off] : 0;
        __syncthreads();
        s[t] += u;
        __syncthreads();
    }
    if (t < NBUCK) {
        int base = s[t] - v;
        bbase[t] = base;
        bcur[t] = base;
    }
    if (t == 0) rowptr[N_NODES] = N_EDGES;
}

// ---------------------------------------------------------------------------
// Pass A: scatter edges into 782 row-buckets (row >> 7).
// ---------------------------------------------------------------------------
__global__ __launch_bounds__(256) void bucket_kernel(const int* __restrict__ row,
                                                     const int* __restrict__ col,
                                                     const float* __restrict__ ew,
                                                     int* __restrict__ bcur,
                                                     int2* __restrict__ bucketed) {
    __shared__ int lcnt[NBUCK];
    __shared__ int lbase[NBUCK];
    const int t = threadIdx.x;
    for (int b = t; b < NBUCK; b += 256) lcnt[b] = 0;
    __syncthreads();

    const int e0 = blockIdx.x * CHUNK;
    int bk[16];
    int val[16];
    float w[16];
    #pragma unroll
    for (int i = 0; i < 16; i++) {
        int e = e0 + i * 256 + t;
        if (e < N_EDGES) {
            int r = row[e];
            int c = col[e];
            w[i] = ew[e];
            bk[i] = r >> BSHIFT;
            val[i] = ((r & ((1 << BSHIFT) - 1)) << 17) | c;
            atomicAdd(&lcnt[bk[i]], 1);
        } else {
            bk[i] = -1;
        }
    }
    __syncthreads();

    for (int b = t; b < NBUCK; b += 256) {
        int c = lcnt[b];
        lbase[b] = c ? atomicAdd(&bcur[b], c) : 0;
        lcnt[b] = 0;   // reuse as rank counter
    }
    __syncthreads();

    #pragma unroll
    for (int i = 0; i < 16; i++) {
        if (bk[i] >= 0) {
            int pos = lbase[bk[i]] + atomicAdd(&lcnt[bk[i]], 1);
            bucketed[pos] = make_int2(val[i], __float_as_int(w[i]));
        }
    }
}

// ---------------------------------------------------------------------------
// Pass B: per-bucket LDS counting sort; also emits rowptr. No global atomics.
// ---------------------------------------------------------------------------
__global__ __launch_bounds__(256) void place_kernel(const int* __restrict__ bbase,
                                                    const int* __restrict__ hb,
                                                    const int2* __restrict__ bucketed,
                                                    int2* __restrict__ sorted,
                                                    int* __restrict__ rowptr) {
    __shared__ int2 stage[CAP];    // 20KB
    __shared__ int2 stage2[CAP];   // 20KB
    __shared__ int hcnt[128];
    __shared__ int hs[128];
    const int t = threadIdx.x;
    const int b = blockIdx.x;
    const int bs = bbase[b];
    const int nrec = hb[b];
    const bool fit = (nrec <= CAP);

    if (t < 128) hcnt[t] = 0;
    __syncthreads();

    for (int i = t; i < nrec; i += 256) {
        int2 rec = bucketed[bs + i];
        if (fit) stage[i] = rec;
        atomicAdd(&hcnt[rec.x >> 17], 1);
    }
    __syncthreads();

    // Hillis-Steele inclusive scan over 128 counters.
    int v0 = (t < 128) ? hcnt[t] : 0;
    if (t < 128) hs[t] = v0;
    __syncthreads();
    #pragma unroll
    for (int off = 1; off < 128; off <<= 1) {
        int u = (t < 128 && t >= off) ? hs[t - off] : 0;
        __syncthreads();
        if (t < 128) hs[t] += u;
        __syncthreads();
    }
    if (t < 128) {
        int excl = hs[t] - v0;
        int r = (b << BSHIFT) + t;
        if (r < N_NODES) rowptr[r] = bs + excl;
        hcnt[t] = excl;
    }
    __syncthreads();

    if (fit) {
        for (int i = t; i < nrec; i += 256) {
            int2 rec = stage[i];
            int lr = rec.x >> 17;
            int pos = atomicAdd(&hcnt[lr], 1);
            stage2[pos] = make_int2(rec.x & 0x1FFFF, rec.y);
        }
        __syncthreads();
        for (int i = t; i < nrec; i += 256) {
            sorted[bs + i] = stage2[i];
        }
    } else {
        for (int i = t; i < nrec; i += 256) {
            int2 rec = bucketed[bs + i];
            int lr = rec.x >> 17;
            int pos = atomicAdd(&hcnt[lr], 1);
            sorted[bs + pos] = make_int2(rec.x & 0x1FFFF, rec.y);
        }
    }
}

// ---------------------------------------------------------------------------
// Gather-reduce (R14): block = 52 contiguous nodes; sorted span staged in LDS;
// inner loop = fixed 16-deep fully-unrolled predicated chunks (clamped LDS
// index, zeroed weight) -> no scalar tail, GDEPTH gathers always in flight.
// __launch_bounds__(256,4): VGPR budget 128, occupancy floor 4 waves/SIMD.
// BN stats fused: block LDS reduce -> 128 atomics per block.
// ---------------------------------------------------------------------------
__global__ __launch_bounds__(256, 4) void gather_kernel(const int* __restrict__ rowptr,
                                                        const int2* __restrict__ sorted,
                                                        const unsigned short* __restrict__ support,
                                                        float* __restrict__ agg,
                                                        float* __restrict__ sums) {
    __shared__ int2 ebuf[ECAP];        // 12 KB
    __shared__ int rp[NPB + 1];
    __shared__ float red[2][4][64];
    const int t = threadIdx.x;
    const int f = t & 63;
    const int wv = t >> 6;
    const int n0 = blockIdx.x * NPB;
    const int n1 = (n0 + NPB < N_NODES) ? n0 + NPB : N_NODES;
    const int nn = n1 - n0;
    float s = 0.f, s2 = 0.f;

    // Stage rowptr span.
    for (int i = t; i <= nn; i += 256) rp[i] = rowptr[n0 + i];
    __syncthreads();
    const int jb0 = rp[0];
    const int tot = rp[nn] - jb0;
    const int stot = (tot < ECAP) ? tot : ECAP;

    // Stage the block's sorted span into LDS (coalesced).
    for (int i = t; i < stot; i += 256) ebuf[i] = sorted[jb0 + i];
    __syncthreads();

    // Each wave: 13 contiguous nodes.
    const int a0n = wv * 13;
    const int b0n = (a0n + 13 < nn) ? a0n + 13 : nn;
    for (int i = a0n; i < b0n; i++) {
        const int jb = rp[i] - jb0;
        const int je = rp[i + 1] - jb0;
        const int elim = (je < stot) ? je : stot;
        float acc0 = 0.f, acc1 = 0.f;

        for (int base = jb; base < elim; base += GDEPTH) {
            int cidx[GDEPTH];
            int2 mm[GDEPTH];
            float ww[GDEPTH];
            unsigned short uu[GDEPTH];
            #pragma unroll
            for (int k = 0; k < GDEPTH; k++) {
                int idx = base + k;
                cidx[k] = (idx < elim) ? idx : elim - 1;   // elim > jb here
                mm[k] = ebuf[cidx[k]];
                ww[k] = (idx < elim) ? __uint_as_float(mm[k].y) : 0.0f;
            }
            #pragma unroll
            for (int k = 0; k < GDEPTH; k++) {
                uu[k] = support[mm[k].x * NHID + f];
            }
            #pragma unroll
            for (int k = 0; k < GDEPTH; k++) {
                if (k & 1) acc1 = fmaf(ww[k], bf2f(uu[k]), acc1);
                else       acc0 = fmaf(ww[k], bf2f(uu[k]), acc0);
            }
        }
        // Overflow fallback (tot > ECAP): metadata direct from global (~never).
        for (int e = elim; e < je; ++e) {
            int2 m = sorted[jb0 + e];
            acc0 = fmaf(__uint_as_float(m.y), bf2f(support[m.x * NHID + f]), acc0);
        }
        float acc = acc0 + acc1;
        agg[(size_t)(n0 + i) * NHID + f] = acc;
        s += acc;
        s2 = fmaf(acc, acc, s2);
    }

    red[0][wv][f] = s;
    red[1][wv][f] = s2;
    __syncthreads();
    if (t < 64) {
        atomicAdd(&sums[f], red[0][0][f] + red[0][1][f] + red[0][2][f] + red[0][3][f]);
    } else if (t < 128) {
        atomicAdd(&sums[64 + f], red[1][0][f] + red[1][1][f] + red[1][2][f] + red[1][3][f]);
    }
}

// ---------------------------------------------------------------------------
// Finalize: scale = gamma*rsqrt(var+eps); shift = beta - mean*scale.
// ---------------------------------------------------------------------------
__global__ __launch_bounds__(64) void finalize_kernel(const float* __restrict__ sums,
                                                      const float* __restrict__ gamma,
                                                      const float* __restrict__ beta,
                                                      float* __restrict__ scaleshift) {
    const int f = threadIdx.x;
    const float inv_n = 1.0f / (float)N_NODES;
    float mean = sums[f] * inv_n;
    float var = sums[64 + f] * inv_n - mean * mean;
    float sc = gamma[f] * rsqrtf(var + 1e-5f);
    scaleshift[f] = sc;
    scaleshift[64 + f] = beta[f] - mean * sc;
}

// ---------------------------------------------------------------------------
// Threefry-2x32, 20 rounds, key=(0,42). Hand-verified vs JAX test vector.
// ---------------------------------------------------------------------------
__device__ __forceinline__ uint32_t rotl32(uint32_t x, int d) {
    return (x << d) | (x >> (32 - d));
}

__device__ __forceinline__ void threefry2x32_0_42(uint32_t x0, uint32_t x1,
                                                  uint32_t& o0, uint32_t& o1) {
    const uint32_t k0 = 0u, k1 = 42u;
    const uint32_t k2 = k0 ^ k1 ^ 0x1BD11BDAu;
    x0 += k0; x1 += k1;
    x0 += x1; x1 = rotl32(x1, 13) ^ x0;
    x0 += x1; x1 = rotl32(x1, 15) ^ x0;
    x0 += x1; x1 = rotl32(x1, 26) ^ x0;
    x0 += x1; x1 = rotl32(x1, 6)  ^ x0;
    x0 += k1; x1 += k2 + 1u;
    x0 += x1; x1 = rotl32(x1, 17) ^ x0;
    x0 += x1; x1 = rotl32(x1, 29) ^ x0;
    x0 += x1; x1 = rotl32(x1, 16) ^ x0;
    x0 += x1; x1 = rotl32(x1, 24) ^ x0;
    x0 += k2; x1 += k0 + 2u;
    x0 += x1; x1 = rotl32(x1, 13) ^ x0;
    x0 += x1; x1 = rotl32(x1, 15) ^ x0;
    x0 += x1; x1 = rotl32(x1, 26) ^ x0;
    x0 += x1; x1 = rotl32(x1, 6)  ^ x0;
    x0 += k0; x1 += k1 + 3u;
    x0 += x1; x1 = rotl32(x1, 17) ^ x0;
    x0 += x1; x1 = rotl32(x1, 29) ^ x0;
    x0 += x1; x1 = rotl32(x1, 16) ^ x0;
    x0 += x1; x1 = rotl32(x1, 24) ^ x0;
    x0 += k1; x1 += k2 + 4u;
    x0 += x1; x1 = rotl32(x1, 13) ^ x0;
    x0 += x1; x1 = rotl32(x1, 15) ^ x0;
    x0 += x1; x1 = rotl32(x1, 26) ^ x0;
    x0 += x1; x1 = rotl32(x1, 6)  ^ x0;
    x0 += k2; x1 += k0 + 5u;
    o0 = x0; o1 = x1;
}

// ---------------------------------------------------------------------------
// Apply: BN affine + ReLU + dropout; f32 out (overwrites dead support).
// ---------------------------------------------------------------------------
__global__ __launch_bounds__(256) void apply_kernel(const float* __restrict__ agg,
                                                    const float* __restrict__ scaleshift,
                                                    float* __restrict__ out) {
    const int i = blockIdx.x * 256 + threadIdx.x;
    if (i >= N_ELEMS) return;
    const int f = i & 63;
    const float sc = scaleshift[f];
    const float sh = scaleshift[64 + f];

    uint32_t o0, o1;
    threefry2x32_0_42(0u, (uint32_t)i, o0, o1);
    uint32_t bits = o0 ^ o1;
    float u = __uint_as_float((bits >> 9) | 0x3F800000u) - 1.0f;

    float v = fmaxf(fmaf(agg[i], sc, sh), 0.0f);
    out[i] = (u < 0.7f) ? v * (1.0f / 0.7f) : 0.0f;
}

// ---------------------------------------------------------------------------
extern "C" void kernel_launch(void* const* d_in, const int* in_sizes, int n_in,
                              void* d_out, int out_size, void* d_ws, size_t ws_size,
                              hipStream_t stream) {
    const float* x     = (const float*)d_in[0];
    const int*   row   = (const int*)d_in[1];
    const int*   col   = (const int*)d_in[2];
    const float* ew    = (const float*)d_in[3];
    const float* W     = (const float*)d_in[4];
    const float* gamma = (const float*)d_in[6];
    const float* beta  = (const float*)d_in[7];
    float* out = (float*)d_out;

    float* sums       = (float*)d_ws;                      // 128 f32
    int*   hb         = (int*)(sums + 128);                // 1024 i32 (782 used)
    float* scaleshift = (float*)(hb + 1024);               // 128 f32
    int*   bbase      = (int*)(scaleshift + 128);          // 1024 i32
    int*   bcur       = bbase + 1024;                      // 1024 i32
    int*   rowptr     = bcur + 1024;                       // 100004 i32
    unsigned short* wt = (unsigned short*)(rowptr + 100004); // 16384 ushort
    float* agg        = (float*)(wt + 16384);              // 6.4M f32
    int2*  sorted     = (int2*)(agg + (size_t)N_ELEMS);    // 1.6M int2
    unsigned short* support = (unsigned short*)out;        // 6.4M bf16, in d_out
    int2*  bucketed   = (int2*)agg;                        // aliases agg (dead)

    // zero sums + hb (adjacent)
    hipMemsetAsync(d_ws, 0, (size_t)(128 + 1024) * 4, stream);

    wtprep_kernel<<<64, 256, 0, stream>>>(W, wt);
    gemm_kernel<<<(N_NODES + 63) / 64, 256, 0, stream>>>(x, wt, support);

    bhist_kernel<<<NBBLK, 256, 0, stream>>>(row, hb);
    bscan_kernel<<<1, 1024, 0, stream>>>(hb, bbase, bcur, rowptr);
    bucket_kernel<<<NBBLK, 256, 0, stream>>>(row, col, ew, bcur, bucketed);
    place_kernel<<<NBUCK, 256, 0, stream>>>(bbase, hb, bucketed, sorted, rowptr);

    gather_kernel<<<GBLK, 256, 0, stream>>>(rowptr, sorted, support, agg, sums);

    finalize_kernel<<<1, 64, 0, stream>>>(sums, gamma, beta, scaleshift);
    apply_kernel<<<(N_ELEMS + 255) / 256, 256, 0, stream>>>(agg, scaleshift, out);
}

// Round 6
// 338.835 us; speedup vs baseline: 1.0251x; 1.0251x over previous
//
#include <hip/hip_runtime.h>
#include <stdint.h>

#define N_NODES 100000
#define N_EDGES 1600000
#define NFEAT 256
#define NHID 64
#define N_ELEMS (N_NODES * NHID)   // 6,400,000

// R11: row-buckets of 128 rows; per-bucket LDS counting sort.
#define BSHIFT 7
#define NBUCK 782                  // ceil(100000/128)
#define CHUNK 4096                 // edges per bhist/bucket block
#define NBBLK ((N_EDGES + CHUNK - 1) / CHUNK)   // 391
#define CAP 2560                   // stage capacity; mean 2048, sigma ~45 -> +11s

// R13..R15 gather: block = 52 contiguous nodes, metadata staged in LDS.
#define NPB 52                     // nodes per block
#define GBLK ((N_NODES + NPB - 1) / NPB)        // 1924
#define ECAP 1536                  // LDS edge records; mean 832, sigma 29 -> +24s

// Config (validated R6/R7): inputs f32, output f32, dropout = JAX partitionable
// threefry (key=(0,42), counter (0,i), bits = o0^o1).
//
// R14 post-mortem: dur pinned ~83us across 3 structurally different gathers;
//   VGPR 36 -> compiler never held 16 scalar gathers in flight (needs >32
//   VGPRs); VALUBusy 23->45% with flat dur = predication filled idle slots,
//   critical path unmoved. Invariant: 1 gather instr/edge, 2B/lane.
// R15: reshape the gather. Lane loads uint2 (8B = 4 bf16 features), 16 lanes
//   per support row -> ONE wave instruction gathers 4 edges (quarters q=0..3).
//   4x fewer gather instrs, 4 edges per vmcnt slot, ~3x less VALU/edge
//   (packed unpack: u32<<16 / u32&0xFFFF0000). Per node: quarter-combine via
//   shfl_xor(16,32), 16-lane float4 row store. No tail (clamped predication);
//   overflow fallback starts at max(jb, elim).
//
// ws layout:
//   sums[128] f32 | hb[1024] i32 | scaleshift[128] f32 | bbase[1024] i32
//   | bcur[1024] i32 | rowptr[100004] i32 | wt[16384] ushort
//   | agg[6.4M] f32 | sorted[1.6M] int2
// support[6.4M] bf16 staged in d_out (dead before apply overwrites).
// bucketed[1.6M] int2 aliases agg (dead until gather writes agg).

typedef __attribute__((ext_vector_type(8))) short bf16x8;
typedef __attribute__((ext_vector_type(4))) float f32x4;

__device__ __forceinline__ unsigned short f2bf(float f) {
    uint32_t u = __float_as_uint(f);
    u += 0x7FFFu + ((u >> 16) & 1u);   // RNE
    return (unsigned short)(u >> 16);
}
__device__ __forceinline__ float bf2f(unsigned short u) {
    return __uint_as_float(((uint32_t)u) << 16);
}

// ---------------------------------------------------------------------------
// W^T prep: wt[n][k] = bf16(W[k][n])
// ---------------------------------------------------------------------------
__global__ __launch_bounds__(256) void wtprep_kernel(const float* __restrict__ W,
                                                     unsigned short* __restrict__ wt) {
    int i = blockIdx.x * 256 + threadIdx.x;
    if (i < NFEAT * NHID) {
        int k = i >> 6, n = i & 63;
        wt[n * NFEAT + k] = f2bf(W[i]);
    }
}

// ---------------------------------------------------------------------------
// GEMM (MFMA bf16): support[N x 64] = x[N x 256] @ W[256 x 64], bf16 out.
// ---------------------------------------------------------------------------
__global__ __launch_bounds__(256) void gemm_kernel(const float* __restrict__ x,
                                                   const unsigned short* __restrict__ wt,
                                                   unsigned short* __restrict__ support) {
    __shared__ unsigned short Abf[64][264];  // row stride 528B, 16B-aligned
    __shared__ unsigned short Bt[64][264];   // Bt[n][k]
    const int t = threadIdx.x;
    const int row0 = blockIdx.x * 64;

    {
        const int r = t >> 6;
        const int c4 = t & 63;
        #pragma unroll
        for (int rr = 0; rr < 16; rr++) {
            int lr_ = rr * 4 + r;
            int gr = row0 + lr_;
            float4 v = make_float4(0.f, 0.f, 0.f, 0.f);
            if (gr < N_NODES) v = *(const float4*)&x[(size_t)gr * NFEAT + c4 * 4];
            ushort4 u;
            u.x = f2bf(v.x); u.y = f2bf(v.y); u.z = f2bf(v.z); u.w = f2bf(v.w);
            *(ushort4*)&Abf[lr_][c4 * 4] = u;
        }
    }
    {
        const int rB = t >> 5;
        const int ch = t & 31;
        #pragma unroll
        for (int rr = 0; rr < 8; rr++) {
            int n = rr * 8 + rB;
            uint4 v = *(const uint4*)&wt[n * NFEAT + ch * 8];
            *(uint4*)&Bt[n][ch * 8] = v;
        }
    }
    __syncthreads();

    const int lane = t & 63;
    const int w = t >> 6;
    const int m = lane & 15;
    const int q = lane >> 4;
    f32x4 acc0 = {0.f, 0.f, 0.f, 0.f};
    f32x4 acc1 = acc0, acc2 = acc0, acc3 = acc0;

    #pragma unroll
    for (int ks = 0; ks < NFEAT; ks += 32) {
        bf16x8 af = *(const bf16x8*)&Abf[w * 16 + m][ks + q * 8];
        bf16x8 b0 = *(const bf16x8*)&Bt[ 0 + m][ks + q * 8];
        bf16x8 b1 = *(const bf16x8*)&Bt[16 + m][ks + q * 8];
        bf16x8 b2 = *(const bf16x8*)&Bt[32 + m][ks + q * 8];
        bf16x8 b3 = *(const bf16x8*)&Bt[48 + m][ks + q * 8];
        acc0 = __builtin_amdgcn_mfma_f32_16x16x32_bf16(af, b0, acc0, 0, 0, 0);
        acc1 = __builtin_amdgcn_mfma_f32_16x16x32_bf16(af, b1, acc1, 0, 0, 0);
        acc2 = __builtin_amdgcn_mfma_f32_16x16x32_bf16(af, b2, acc2, 0, 0, 0);
        acc3 = __builtin_amdgcn_mfma_f32_16x16x32_bf16(af, b3, acc3, 0, 0, 0);
    }

    // C/D layout: row = q*4 + reg, col = nt*16 + m
    #pragma unroll
    for (int reg = 0; reg < 4; reg++) {
        int grow = row0 + w * 16 + q * 4 + reg;
        if (grow < N_NODES) {
            support[(size_t)grow * NHID +  0 + m] = f2bf(acc0[reg]);
            support[(size_t)grow * NHID + 16 + m] = f2bf(acc1[reg]);
            support[(size_t)grow * NHID + 32 + m] = f2bf(acc2[reg]);
            support[(size_t)grow * NHID + 48 + m] = f2bf(acc3[reg]);
        }
    }
}

// ---------------------------------------------------------------------------
// Bucket-level histogram (LDS-aggregated).
// ---------------------------------------------------------------------------
__global__ __launch_bounds__(256) void bhist_kernel(const int* __restrict__ row,
                                                    int* __restrict__ hb) {
    __shared__ int lcnt[NBUCK];
    const int t = threadIdx.x;
    for (int b = t; b < NBUCK; b += 256) lcnt[b] = 0;
    __syncthreads();
    const int e0 = blockIdx.x * CHUNK;
    #pragma unroll
    for (int i = 0; i < 16; i++) {
        int e = e0 + i * 256 + t;
        if (e < N_EDGES) atomicAdd(&lcnt[row[e] >> BSHIFT], 1);
    }
    __syncthreads();
    for (int b = t; b < NBUCK; b += 256) {
        int c = lcnt[b];
        if (c) atomicAdd(&hb[b], c);
    }
}

// ---------------------------------------------------------------------------
// Exclusive scan of bucket counts -> bucket bases; seed bucket cursors.
// ---------------------------------------------------------------------------
__global__ __launch_bounds__(1024) void bscan_kernel(const int* __restrict__ hb,
                                                     int* __restrict__ bbase,
                                                     int* __restrict__ bcur,
                                                     int* __restrict__ rowptr) {
    __shared__ int s[1024];
    const int t = threadIdx.x;
    int v = (t < NBUCK) ? hb[t] : 0;
    s[t] = v;
    __syncthreads();
    #pragma unroll
    for (int off = 1; off < 1024; off <<= 1) {
        int u = (t >= off) ? s[t - off] : 0;
        __syncthreads();
        s[t] += u;
        __syncthreads();
    }
    if (t < NBUCK) {
        int base = s[t] - v;
        bbase[t] = base;
        bcur[t] = base;
    }
    if (t == 0) rowptr[N_NODES] = N_EDGES;
}

// ---------------------------------------------------------------------------
// Pass A: scatter edges into 782 row-buckets (row >> 7).
// ---------------------------------------------------------------------------
__global__ __launch_bounds__(256) void bucket_kernel(const int* __restrict__ row,
                                                     const int* __restrict__ col,
                                                     const float* __restrict__ ew,
                                                     int* __restrict__ bcur,
                                                     int2* __restrict__ bucketed) {
    __shared__ int lcnt[NBUCK];
    __shared__ int lbase[NBUCK];
    const int t = threadIdx.x;
    for (int b = t; b < NBUCK; b += 256) lcnt[b] = 0;
    __syncthreads();

    const int e0 = blockIdx.x * CHUNK;
    int bk[16];
    int val[16];
    float w[16];
    #pragma unroll
    for (int i = 0; i < 16; i++) {
        int e = e0 + i * 256 + t;
        if (e < N_EDGES) {
            int r = row[e];
            int c = col[e];
            w[i] = ew[e];
            bk[i] = r >> BSHIFT;
            val[i] = ((r & ((1 << BSHIFT) - 1)) << 17) | c;
            atomicAdd(&lcnt[bk[i]], 1);
        } else {
            bk[i] = -1;
        }
    }
    __syncthreads();

    for (int b = t; b < NBUCK; b += 256) {
        int c = lcnt[b];
        lbase[b] = c ? atomicAdd(&bcur[b], c) : 0;
        lcnt[b] = 0;   // reuse as rank counter
    }
    __syncthreads();

    #pragma unroll
    for (int i = 0; i < 16; i++) {
        if (bk[i] >= 0) {
            int pos = lbase[bk[i]] + atomicAdd(&lcnt[bk[i]], 1);
            bucketed[pos] = make_int2(val[i], __float_as_int(w[i]));
        }
    }
}

// ---------------------------------------------------------------------------
// Pass B: per-bucket LDS counting sort; also emits rowptr. No global atomics.
// ---------------------------------------------------------------------------
__global__ __launch_bounds__(256) void place_kernel(const int* __restrict__ bbase,
                                                    const int* __restrict__ hb,
                                                    const int2* __restrict__ bucketed,
                                                    int2* __restrict__ sorted,
                                                    int* __restrict__ rowptr) {
    __shared__ int2 stage[CAP];    // 20KB
    __shared__ int2 stage2[CAP];   // 20KB
    __shared__ int hcnt[128];
    __shared__ int hs[128];
    const int t = threadIdx.x;
    const int b = blockIdx.x;
    const int bs = bbase[b];
    const int nrec = hb[b];
    const bool fit = (nrec <= CAP);

    if (t < 128) hcnt[t] = 0;
    __syncthreads();

    for (int i = t; i < nrec; i += 256) {
        int2 rec = bucketed[bs + i];
        if (fit) stage[i] = rec;
        atomicAdd(&hcnt[rec.x >> 17], 1);
    }
    __syncthreads();

    // Hillis-Steele inclusive scan over 128 counters.
    int v0 = (t < 128) ? hcnt[t] : 0;
    if (t < 128) hs[t] = v0;
    __syncthreads();
    #pragma unroll
    for (int off = 1; off < 128; off <<= 1) {
        int u = (t < 128 && t >= off) ? hs[t - off] : 0;
        __syncthreads();
        if (t < 128) hs[t] += u;
        __syncthreads();
    }
    if (t < 128) {
        int excl = hs[t] - v0;
        int r = (b << BSHIFT) + t;
        if (r < N_NODES) rowptr[r] = bs + excl;
        hcnt[t] = excl;
    }
    __syncthreads();

    if (fit) {
        for (int i = t; i < nrec; i += 256) {
            int2 rec = stage[i];
            int lr = rec.x >> 17;
            int pos = atomicAdd(&hcnt[lr], 1);
            stage2[pos] = make_int2(rec.x & 0x1FFFF, rec.y);
        }
        __syncthreads();
        for (int i = t; i < nrec; i += 256) {
            sorted[bs + i] = stage2[i];
        }
    } else {
        for (int i = t; i < nrec; i += 256) {
            int2 rec = bucketed[bs + i];
            int lr = rec.x >> 17;
            int pos = atomicAdd(&hcnt[lr], 1);
            sorted[bs + pos] = make_int2(rec.x & 0x1FFFF, rec.y);
        }
    }
}

// ---------------------------------------------------------------------------
// Gather-reduce (R15): block = 52 contiguous nodes; sorted span staged in LDS.
// Quad-split wave: quarter q = lane>>4 handles edge (base + g*4 + q); lane
// fl = lane&15 loads uint2 = features [4fl, 4fl+4) of that edge's support
// row -> one instruction gathers 4 edges. Per node: combine quarters with
// shfl_xor(16,32); lanes 0..15 store the float4 agg row and track BN sums.
// __launch_bounds__(256,4): VGPR budget 128.
// ---------------------------------------------------------------------------
__global__ __launch_bounds__(256, 4) void gather_kernel(const int* __restrict__ rowptr,
                                                        const int2* __restrict__ sorted,
                                                        const unsigned short* __restrict__ support,
                                                        float* __restrict__ agg,
                                                        float* __restrict__ sums) {
    __shared__ int2 ebuf[ECAP];        // 12 KB
    __shared__ int rp[NPB + 1];
    __shared__ float red[2][4][64];
    const int t = threadIdx.x;
    const int lane = t & 63;
    const int wv = t >> 6;
    const int q = lane >> 4;       // edge quarter
    const int fl = lane & 15;      // feature slot: features [4fl, 4fl+4)
    const int n0 = blockIdx.x * NPB;
    const int n1 = (n0 + NPB < N_NODES) ? n0 + NPB : N_NODES;
    const int nn = n1 - n0;

    float s0 = 0.f, s1 = 0.f, s2 = 0.f, s3 = 0.f;
    float z0 = 0.f, z1 = 0.f, z2 = 0.f, z3 = 0.f;

    // Stage rowptr span.
    for (int i = t; i <= nn; i += 256) rp[i] = rowptr[n0 + i];
    __syncthreads();
    const int jb0 = rp[0];
    const int tot = rp[nn] - jb0;
    const int stot = (tot < ECAP) ? tot : ECAP;

    // Stage the block's sorted span into LDS (coalesced).
    for (int i = t; i < stot; i += 256) ebuf[i] = sorted[jb0 + i];
    __syncthreads();

    // Each wave: 13 contiguous nodes.
    const int a0n = wv * 13;
    const int b0n = (a0n + 13 < nn) ? a0n + 13 : nn;
    for (int i = a0n; i < b0n; i++) {
        const int jb = rp[i] - jb0;
        const int je = rp[i + 1] - jb0;
        const int elim = (je < stot) ? je : stot;
        float a0 = 0.f, a1 = 0.f, a2 = 0.f, a3 = 0.f;

        // Main: chunks of 16 edges = 4 groups x 4 edges (quarters).
        for (int base = jb; base < elim; base += 16) {
            int2  mm[4];
            float ww[4];
            uint2 vv[4];
            #pragma unroll
            for (int g = 0; g < 4; g++) {
                int idx = base + (g << 2) + q;
                int ci = (idx < elim) ? idx : elim - 1;
                mm[g] = ebuf[ci];
                ww[g] = (idx < elim) ? __uint_as_float(mm[g].y) : 0.0f;
            }
            #pragma unroll
            for (int g = 0; g < 4; g++) {
                vv[g] = *(const uint2*)(support + (((size_t)(unsigned)mm[g].x) << 6) + (fl << 2));
            }
            #pragma unroll
            for (int g = 0; g < 4; g++) {
                a0 = fmaf(ww[g], __uint_as_float(vv[g].x << 16), a0);
                a1 = fmaf(ww[g], __uint_as_float(vv[g].x & 0xFFFF0000u), a1);
                a2 = fmaf(ww[g], __uint_as_float(vv[g].y << 16), a2);
                a3 = fmaf(ww[g], __uint_as_float(vv[g].y & 0xFFFF0000u), a3);
            }
        }

        // Overflow fallback (tot > ECAP, ~never): metadata direct from global.
        const int fb = (jb > elim) ? jb : elim;
        for (int base = fb; base < je; base += 4) {
            int idx = base + q;
            int ci = (idx < je) ? idx : je - 1;
            int2 m = sorted[jb0 + ci];
            float w = (idx < je) ? __uint_as_float(m.y) : 0.0f;
            uint2 v = *(const uint2*)(support + (((size_t)(unsigned)m.x) << 6) + (fl << 2));
            a0 = fmaf(w, __uint_as_float(v.x << 16), a0);
            a1 = fmaf(w, __uint_as_float(v.x & 0xFFFF0000u), a1);
            a2 = fmaf(w, __uint_as_float(v.y << 16), a2);
            a3 = fmaf(w, __uint_as_float(v.y & 0xFFFF0000u), a3);
        }

        // Combine the 4 quarters (each holds the same feature slots).
        a0 += __shfl_xor(a0, 16); a0 += __shfl_xor(a0, 32);
        a1 += __shfl_xor(a1, 16); a1 += __shfl_xor(a1, 32);
        a2 += __shfl_xor(a2, 16); a2 += __shfl_xor(a2, 32);
        a3 += __shfl_xor(a3, 16); a3 += __shfl_xor(a3, 32);

        if (lane < 16) {
            float4 o = make_float4(a0, a1, a2, a3);
            *(float4*)&agg[(size_t)(n0 + i) * NHID + (fl << 2)] = o;
            s0 += a0; s1 += a1; s2 += a2; s3 += a3;
            z0 = fmaf(a0, a0, z0); z1 = fmaf(a1, a1, z1);
            z2 = fmaf(a2, a2, z2); z3 = fmaf(a3, a3, z3);
        }
    }

    if (lane < 16) {
        red[0][wv][(fl << 2) + 0] = s0;
        red[0][wv][(fl << 2) + 1] = s1;
        red[0][wv][(fl << 2) + 2] = s2;
        red[0][wv][(fl << 2) + 3] = s3;
        red[1][wv][(fl << 2) + 0] = z0;
        red[1][wv][(fl << 2) + 1] = z1;
        red[1][wv][(fl << 2) + 2] = z2;
        red[1][wv][(fl << 2) + 3] = z3;
    }
    __syncthreads();
    if (t < 64) {
        atomicAdd(&sums[t], red[0][0][t] + red[0][1][t] + red[0][2][t] + red[0][3][t]);
    } else if (t < 128) {
        int f = t - 64;
        atomicAdd(&sums[64 + f], red[1][0][f] + red[1][1][f] + red[1][2][f] + red[1][3][f]);
    }
}

// ---------------------------------------------------------------------------
// Finalize: scale = gamma*rsqrt(var+eps); shift = beta - mean*scale.
// ---------------------------------------------------------------------------
__global__ __launch_bounds__(64) void finalize_kernel(const float* __restrict__ sums,
                                                      const float* __restrict__ gamma,
                                                      const float* __restrict__ beta,
                                                      float* __restrict__ scaleshift) {
    const int f = threadIdx.x;
    const float inv_n = 1.0f / (float)N_NODES;
    float mean = sums[f] * inv_n;
    float var = sums[64 + f] * inv_n - mean * mean;
    float sc = gamma[f] * rsqrtf(var + 1e-5f);
    scaleshift[f] = sc;
    scaleshift[64 + f] = beta[f] - mean * sc;
}

// ---------------------------------------------------------------------------
// Threefry-2x32, 20 rounds, key=(0,42). Hand-verified vs JAX test vector.
// ---------------------------------------------------------------------------
__device__ __forceinline__ uint32_t rotl32(uint32_t x, int d) {
    return (x << d) | (x >> (32 - d));
}

__device__ __forceinline__ void threefry2x32_0_42(uint32_t x0, uint32_t x1,
                                                  uint32_t& o0, uint32_t& o1) {
    const uint32_t k0 = 0u, k1 = 42u;
    const uint32_t k2 = k0 ^ k1 ^ 0x1BD11BDAu;
    x0 += k0; x1 += k1;
    x0 += x1; x1 = rotl32(x1, 13) ^ x0;
    x0 += x1; x1 = rotl32(x1, 15) ^ x0;
    x0 += x1; x1 = rotl32(x1, 26) ^ x0;
    x0 += x1; x1 = rotl32(x1, 6)  ^ x0;
    x0 += k1; x1 += k2 + 1u;
    x0 += x1; x1 = rotl32(x1, 17) ^ x0;
    x0 += x1; x1 = rotl32(x1, 29) ^ x0;
    x0 += x1; x1 = rotl32(x1, 16) ^ x0;
    x0 += x1; x1 = rotl32(x1, 24) ^ x0;
    x0 += k2; x1 += k0 + 2u;
    x0 += x1; x1 = rotl32(x1, 13) ^ x0;
    x0 += x1; x1 = rotl32(x1, 15) ^ x0;
    x0 += x1; x1 = rotl32(x1, 26) ^ x0;
    x0 += x1; x1 = rotl32(x1, 6)  ^ x0;
    x0 += k0; x1 += k1 + 3u;
    x0 += x1; x1 = rotl32(x1, 17) ^ x0;
    x0 += x1; x1 = rotl32(x1, 29) ^ x0;
    x0 += x1; x1 = rotl32(x1, 16) ^ x0;
    x0 += x1; x1 = rotl32(x1, 24) ^ x0;
    x0 += k1; x1 += k2 + 4u;
    x0 += x1; x1 = rotl32(x1, 13) ^ x0;
    x0 += x1; x1 = rotl32(x1, 15) ^ x0;
    x0 += x1; x1 = rotl32(x1, 26) ^ x0;
    x0 += x1; x1 = rotl32(x1, 6)  ^ x0;
    x0 += k2; x1 += k0 + 5u;
    o0 = x0; o1 = x1;
}

// ---------------------------------------------------------------------------
// Apply: BN affine + ReLU + dropout; f32 out (overwrites dead support).
// ---------------------------------------------------------------------------
__global__ __launch_bounds__(256) void apply_kernel(const float* __restrict__ agg,
                                                    const float* __restrict__ scaleshift,
                                                    float* __restrict__ out) {
    const int i = blockIdx.x * 256 + threadIdx.x;
    if (i >= N_ELEMS) return;
    const int f = i & 63;
    const float sc = scaleshift[f];
    const float sh = scaleshift[64 + f];

    uint32_t o0, o1;
    threefry2x32_0_42(0u, (uint32_t)i, o0, o1);
    uint32_t bits = o0 ^ o1;
    float u = __uint_as_float((bits >> 9) | 0x3F800000u) - 1.0f;

    float v = fmaxf(fmaf(agg[i], sc, sh), 0.0f);
    out[i] = (u < 0.7f) ? v * (1.0f / 0.7f) : 0.0f;
}

// ---------------------------------------------------------------------------
extern "C" void kernel_launch(void* const* d_in, const int* in_sizes, int n_in,
                              void* d_out, int out_size, void* d_ws, size_t ws_size,
                              hipStream_t stream) {
    const float* x     = (const float*)d_in[0];
    const int*   row   = (const int*)d_in[1];
    const int*   col   = (const int*)d_in[2];
    const float* ew    = (const float*)d_in[3];
    const float* W     = (const float*)d_in[4];
    const float* gamma = (const float*)d_in[6];
    const float* beta  = (const float*)d_in[7];
    float* out = (float*)d_out;

    float* sums       = (float*)d_ws;                      // 128 f32
    int*   hb         = (int*)(sums + 128);                // 1024 i32 (782 used)
    float* scaleshift = (float*)(hb + 1024);               // 128 f32
    int*   bbase      = (int*)(scaleshift + 128);          // 1024 i32
    int*   bcur       = bbase + 1024;                      // 1024 i32
    int*   rowptr     = bcur + 1024;                       // 100004 i32
    unsigned short* wt = (unsigned short*)(rowptr + 100004); // 16384 ushort
    float* agg        = (float*)(wt + 16384);              // 6.4M f32
    int2*  sorted     = (int2*)(agg + (size_t)N_ELEMS);    // 1.6M int2
    unsigned short* support = (unsigned short*)out;        // 6.4M bf16, in d_out
    int2*  bucketed   = (int2*)agg;                        // aliases agg (dead)

    // zero sums + hb (adjacent)
    hipMemsetAsync(d_ws, 0, (size_t)(128 + 1024) * 4, stream);

    wtprep_kernel<<<64, 256, 0, stream>>>(W, wt);
    gemm_kernel<<<(N_NODES + 63) / 64, 256, 0, stream>>>(x, wt, support);

    bhist_kernel<<<NBBLK, 256, 0, stream>>>(row, hb);
    bscan_kernel<<<1, 1024, 0, stream>>>(hb, bbase, bcur, rowptr);
    bucket_kernel<<<NBBLK, 256, 0, stream>>>(row, col, ew, bcur, bucketed);
    place_kernel<<<NBUCK, 256, 0, stream>>>(bbase, hb, bucketed, sorted, rowptr);

    gather_kernel<<<GBLK, 256, 0, stream>>>(rowptr, sorted, support, agg, sums);

    finalize_kernel<<<1, 64, 0, stream>>>(sums, gamma, beta, scaleshift);
    apply_kernel<<<(N_ELEMS + 255) / 256, 256, 0, stream>>>(agg, scaleshift, out);
}

// Round 7
// 330.763 us; speedup vs baseline: 1.0501x; 1.0244x over previous
//
#include <hip/hip_runtime.h>
#include <stdint.h>

#define N_NODES 100000
#define N_EDGES 1600000
#define NFEAT 256
#define NHID 64
#define N_ELEMS (N_NODES * NHID)   // 6,400,000

// R11: row-buckets of 128 rows; per-bucket LDS counting sort.
#define BSHIFT 7
#define NBUCK 782                  // ceil(100000/128)
#define CHUNK 4096                 // edges per bhist/bucket block
#define NBBLK ((N_EDGES + CHUNK - 1) / CHUNK)   // 391
#define CAP 2560                   // stage capacity; mean 2048, sigma ~45 -> +11s

// R13..R15 gather: block = 52 contiguous nodes, metadata staged in LDS.
#define NPB 52                     // nodes per block
#define GBLK ((N_NODES + NPB - 1) / NPB)        // 1924
#define ECAP 1536                  // LDS edge records; mean 832, sigma 29 -> +24s

// Config (validated R6/R7): inputs f32, output f32, dropout = JAX partitionable
// threefry (key=(0,42), counter (0,i), bits = o0^o1).
//
// R15 post-mortem: gather 83->72.6us (uint2 quad-gather worked). Accounting:
//   gather is 72.6 of 338.8 total; the ~266us second tier (gemm/bucket/place/
//   apply/...) never shows in top-5 (each <72). Gather near structural floor:
//   FETCH 81MB at ~1.4TB/s TCC-miss rate (12.8MB support thrashing 8x4MB
//   non-coherent L2s).
// R16: attack the second tier.
//   gemm: A-stage deleted (each fragment consumed by one wave); lanes load
//     32B of x per kstep (coalesced 16x128B), convert in regs, MFMA direct.
//     LDS 67.6->33.8KB (2->4 blocks/CU), one barrier fewer.
//   bucket: LDS counting-reorder before scatter (782-bucket block scan) ->
//     linear sweep writes contiguous runs (~12 lines/instr vs ~60).
//   finalize fused into apply (per-thread scale/shift from sums).
//
// ws layout:
//   sums[128] f32 | hb[1024] i32 | bbase[1024] i32 | bcur[1024] i32
//   | rowptr[100004] i32 | wt[16384] ushort | agg[6.4M] f32 | sorted[1.6M] int2
// support[6.4M] bf16 staged in d_out (dead before apply overwrites).
// bucketed[1.6M] int2 aliases agg (dead until gather writes agg).

typedef __attribute__((ext_vector_type(8))) short bf16x8;
typedef __attribute__((ext_vector_type(4))) float f32x4;

__device__ __forceinline__ unsigned short f2bf(float f) {
    uint32_t u = __float_as_uint(f);
    u += 0x7FFFu + ((u >> 16) & 1u);   // RNE
    return (unsigned short)(u >> 16);
}
__device__ __forceinline__ float bf2f(unsigned short u) {
    return __uint_as_float(((uint32_t)u) << 16);
}

// ---------------------------------------------------------------------------
// W^T prep: wt[n][k] = bf16(W[k][n])
// ---------------------------------------------------------------------------
__global__ __launch_bounds__(256) void wtprep_kernel(const float* __restrict__ W,
                                                     unsigned short* __restrict__ wt) {
    int i = blockIdx.x * 256 + threadIdx.x;
    if (i < NFEAT * NHID) {
        int k = i >> 6, n = i & 63;
        wt[n * NFEAT + k] = f2bf(W[i]);
    }
}

// ---------------------------------------------------------------------------
// GEMM (R16): support[N x 64] = x[N x 256] @ W[256 x 64], bf16 out.
// No A staging: lane loads its own 32B of x per kstep (coalesced 16 rows x
// 128B per wave instruction), converts to bf16x8 in regs, MFMA direct.
// LDS = Bt only (33.8KB) -> 4 blocks/CU.
// ---------------------------------------------------------------------------
__global__ __launch_bounds__(256) void gemm_kernel(const float* __restrict__ x,
                                                   const unsigned short* __restrict__ wt,
                                                   unsigned short* __restrict__ support) {
    __shared__ unsigned short Bt[64][264];   // Bt[n][k], row stride 528B
    const int t = threadIdx.x;
    const int row0 = blockIdx.x * 64;

    {
        const int rB = t >> 5;
        const int ch = t & 31;
        #pragma unroll
        for (int rr = 0; rr < 8; rr++) {
            int n = rr * 8 + rB;
            uint4 v = *(const uint4*)&wt[n * NFEAT + ch * 8];
            *(uint4*)&Bt[n][ch * 8] = v;
        }
    }
    __syncthreads();

    const int lane = t & 63;
    const int w = t >> 6;
    const int m = lane & 15;
    const int q = lane >> 4;
    const int growA = row0 + w * 16 + m;
    const int lrow = (growA < N_NODES) ? growA : N_NODES - 1;
    const float* xr = x + (size_t)lrow * NFEAT;

    f32x4 acc0 = {0.f, 0.f, 0.f, 0.f};
    f32x4 acc1 = acc0, acc2 = acc0, acc3 = acc0;

    #pragma unroll
    for (int ks = 0; ks < NFEAT; ks += 32) {
        float4 xa = *(const float4*)&xr[ks + q * 8];
        float4 xb = *(const float4*)&xr[ks + q * 8 + 4];
        ushort4 ua, ub;
        ua.x = f2bf(xa.x); ua.y = f2bf(xa.y); ua.z = f2bf(xa.z); ua.w = f2bf(xa.w);
        ub.x = f2bf(xb.x); ub.y = f2bf(xb.y); ub.z = f2bf(xb.z); ub.w = f2bf(xb.w);
        union { ushort4 u4[2]; bf16x8 v8; } cv;
        cv.u4[0] = ua; cv.u4[1] = ub;
        bf16x8 af = cv.v8;

        bf16x8 b0 = *(const bf16x8*)&Bt[ 0 + m][ks + q * 8];
        bf16x8 b1 = *(const bf16x8*)&Bt[16 + m][ks + q * 8];
        bf16x8 b2 = *(const bf16x8*)&Bt[32 + m][ks + q * 8];
        bf16x8 b3 = *(const bf16x8*)&Bt[48 + m][ks + q * 8];
        acc0 = __builtin_amdgcn_mfma_f32_16x16x32_bf16(af, b0, acc0, 0, 0, 0);
        acc1 = __builtin_amdgcn_mfma_f32_16x16x32_bf16(af, b1, acc1, 0, 0, 0);
        acc2 = __builtin_amdgcn_mfma_f32_16x16x32_bf16(af, b2, acc2, 0, 0, 0);
        acc3 = __builtin_amdgcn_mfma_f32_16x16x32_bf16(af, b3, acc3, 0, 0, 0);
    }

    // C/D layout: row = q*4 + reg, col = nt*16 + m
    #pragma unroll
    for (int reg = 0; reg < 4; reg++) {
        int grow = row0 + w * 16 + q * 4 + reg;
        if (grow < N_NODES) {
            support[(size_t)grow * NHID +  0 + m] = f2bf(acc0[reg]);
            support[(size_t)grow * NHID + 16 + m] = f2bf(acc1[reg]);
            support[(size_t)grow * NHID + 32 + m] = f2bf(acc2[reg]);
            support[(size_t)grow * NHID + 48 + m] = f2bf(acc3[reg]);
        }
    }
}

// ---------------------------------------------------------------------------
// Bucket-level histogram (LDS-aggregated).
// ---------------------------------------------------------------------------
__global__ __launch_bounds__(256) void bhist_kernel(const int* __restrict__ row,
                                                    int* __restrict__ hb) {
    __shared__ int lcnt[NBUCK];
    const int t = threadIdx.x;
    for (int b = t; b < NBUCK; b += 256) lcnt[b] = 0;
    __syncthreads();
    const int e0 = blockIdx.x * CHUNK;
    #pragma unroll
    for (int i = 0; i < 16; i++) {
        int e = e0 + i * 256 + t;
        if (e < N_EDGES) atomicAdd(&lcnt[row[e] >> BSHIFT], 1);
    }
    __syncthreads();
    for (int b = t; b < NBUCK; b += 256) {
        int c = lcnt[b];
        if (c) atomicAdd(&hb[b], c);
    }
}

// ---------------------------------------------------------------------------
// Exclusive scan of bucket counts -> bucket bases; seed bucket cursors.
// ---------------------------------------------------------------------------
__global__ __launch_bounds__(1024) void bscan_kernel(const int* __restrict__ hb,
                                                     int* __restrict__ bbase,
                                                     int* __restrict__ bcur,
                                                     int* __restrict__ rowptr) {
    __shared__ int s[1024];
    const int t = threadIdx.x;
    int v = (t < NBUCK) ? hb[t] : 0;
    s[t] = v;
    __syncthreads();
    #pragma unroll
    for (int off = 1; off < 1024; off <<= 1) {
        int u = (t >= off) ? s[t - off] : 0;
        __syncthreads();
        s[t] += u;
        __syncthreads();
    }
    if (t < NBUCK) {
        int base = s[t] - v;
        bbase[t] = base;
        bcur[t] = base;
    }
    if (t == 0) rowptr[N_NODES] = N_EDGES;
}

// ---------------------------------------------------------------------------
// Pass A (R16): scatter edges into 782 row-buckets with LDS counting-reorder:
// rank records by bucket into an LDS stage (block-level scan of 782 counts),
// then linear sweep -> consecutive threads write consecutive global addresses.
// ---------------------------------------------------------------------------
__global__ __launch_bounds__(256) void bucket_kernel(const int* __restrict__ row,
                                                     const int* __restrict__ col,
                                                     const float* __restrict__ ew,
                                                     int* __restrict__ bcur,
                                                     int2* __restrict__ bucketed) {
    __shared__ int2 stage[CHUNK];              // 32 KB
    __shared__ unsigned short bkid[CHUNK];     // 8 KB
    __shared__ int lcnt[1024];                 // 4 KB (782 used, zero-padded)
    __shared__ int lexcl[1024];                // 4 KB
    __shared__ int lbase[1024];                // 4 KB
    __shared__ int p[256];                     // 1 KB
    const int t = threadIdx.x;
    for (int b = t; b < 1024; b += 256) lcnt[b] = 0;
    __syncthreads();

    const int e0 = blockIdx.x * CHUNK;
    const int ctot = (e0 + CHUNK <= N_EDGES) ? CHUNK : (N_EDGES - e0);
    int bk[16];
    int val[16];
    float w[16];
    #pragma unroll
    for (int i = 0; i < 16; i++) {
        int e = e0 + i * 256 + t;
        if (e < N_EDGES) {
            int r = row[e];
            int c = col[e];
            w[i] = ew[e];
            bk[i] = r >> BSHIFT;
            val[i] = ((r & ((1 << BSHIFT) - 1)) << 17) | c;
            atomicAdd(&lcnt[bk[i]], 1);
        } else {
            bk[i] = -1;
        }
    }
    __syncthreads();

    // Block-level exclusive scan of 1024 bucket counts (4 per thread).
    int s0 = lcnt[t * 4 + 0], s1 = lcnt[t * 4 + 1];
    int s2 = lcnt[t * 4 + 2], s3 = lcnt[t * 4 + 3];
    int tsum = s0 + s1 + s2 + s3;
    p[t] = tsum;
    __syncthreads();
    #pragma unroll
    for (int off = 1; off < 256; off <<= 1) {
        int u = (t >= off) ? p[t - off] : 0;
        __syncthreads();
        p[t] += u;
        __syncthreads();
    }
    int pe = p[t] - tsum;
    lexcl[t * 4 + 0] = pe;
    lexcl[t * 4 + 1] = pe + s0;
    lexcl[t * 4 + 2] = pe + s0 + s1;
    lexcl[t * 4 + 3] = pe + s0 + s1 + s2;

    // Reserve global runs; then reset lcnt for ranking.
    for (int b = t; b < NBUCK; b += 256) {
        int c = lcnt[b];
        lbase[b] = c ? atomicAdd(&bcur[b], c) : 0;
    }
    __syncthreads();
    for (int b = t; b < 1024; b += 256) lcnt[b] = 0;
    __syncthreads();

    // Rank into LDS stage ordered by bucket.
    #pragma unroll
    for (int i = 0; i < 16; i++) {
        if (bk[i] >= 0) {
            int r = atomicAdd(&lcnt[bk[i]], 1);
            int pos = lexcl[bk[i]] + r;
            stage[pos] = make_int2(val[i], __float_as_int(w[i]));
            bkid[pos] = (unsigned short)bk[i];
        }
    }
    __syncthreads();

    // Linear sweep: consecutive threads -> consecutive global addresses.
    for (int i = t; i < ctot; i += 256) {
        int b = bkid[i];
        bucketed[lbase[b] + (i - lexcl[b])] = stage[i];
    }
}

// ---------------------------------------------------------------------------
// Pass B: per-bucket LDS counting sort; also emits rowptr. No global atomics.
// ---------------------------------------------------------------------------
__global__ __launch_bounds__(256) void place_kernel(const int* __restrict__ bbase,
                                                    const int* __restrict__ hb,
                                                    const int2* __restrict__ bucketed,
                                                    int2* __restrict__ sorted,
                                                    int* __restrict__ rowptr) {
    __shared__ int2 stage[CAP];    // 20KB
    __shared__ int2 stage2[CAP];   // 20KB
    __shared__ int hcnt[128];
    __shared__ int hs[128];
    const int t = threadIdx.x;
    const int b = blockIdx.x;
    const int bs = bbase[b];
    const int nrec = hb[b];
    const bool fit = (nrec <= CAP);

    if (t < 128) hcnt[t] = 0;
    __syncthreads();

    for (int i = t; i < nrec; i += 256) {
        int2 rec = bucketed[bs + i];
        if (fit) stage[i] = rec;
        atomicAdd(&hcnt[rec.x >> 17], 1);
    }
    __syncthreads();

    // Hillis-Steele inclusive scan over 128 counters.
    int v0 = (t < 128) ? hcnt[t] : 0;
    if (t < 128) hs[t] = v0;
    __syncthreads();
    #pragma unroll
    for (int off = 1; off < 128; off <<= 1) {
        int u = (t < 128 && t >= off) ? hs[t - off] : 0;
        __syncthreads();
        if (t < 128) hs[t] += u;
        __syncthreads();
    }
    if (t < 128) {
        int excl = hs[t] - v0;
        int r = (b << BSHIFT) + t;
        if (r < N_NODES) rowptr[r] = bs + excl;
        hcnt[t] = excl;
    }
    __syncthreads();

    if (fit) {
        for (int i = t; i < nrec; i += 256) {
            int2 rec = stage[i];
            int lr = rec.x >> 17;
            int pos = atomicAdd(&hcnt[lr], 1);
            stage2[pos] = make_int2(rec.x & 0x1FFFF, rec.y);
        }
        __syncthreads();
        for (int i = t; i < nrec; i += 256) {
            sorted[bs + i] = stage2[i];
        }
    } else {
        for (int i = t; i < nrec; i += 256) {
            int2 rec = bucketed[bs + i];
            int lr = rec.x >> 17;
            int pos = atomicAdd(&hcnt[lr], 1);
            sorted[bs + pos] = make_int2(rec.x & 0x1FFFF, rec.y);
        }
    }
}

// ---------------------------------------------------------------------------
// Gather-reduce (R15): block = 52 contiguous nodes; sorted span staged in LDS.
// Quad-split wave: quarter q = lane>>4 handles edge (base + g*4 + q); lane
// fl = lane&15 loads uint2 = features [4fl, 4fl+4) of that edge's support
// row -> one instruction gathers 4 edges. Per node: combine quarters with
// shfl_xor(16,32); lanes 0..15 store the float4 agg row and track BN sums.
// ---------------------------------------------------------------------------
__global__ __launch_bounds__(256, 4) void gather_kernel(const int* __restrict__ rowptr,
                                                        const int2* __restrict__ sorted,
                                                        const unsigned short* __restrict__ support,
                                                        float* __restrict__ agg,
                                                        float* __restrict__ sums) {
    __shared__ int2 ebuf[ECAP];        // 12 KB
    __shared__ int rp[NPB + 1];
    __shared__ float red[2][4][64];
    const int t = threadIdx.x;
    const int lane = t & 63;
    const int wv = t >> 6;
    const int q = lane >> 4;       // edge quarter
    const int fl = lane & 15;      // feature slot: features [4fl, 4fl+4)
    const int n0 = blockIdx.x * NPB;
    const int n1 = (n0 + NPB < N_NODES) ? n0 + NPB : N_NODES;
    const int nn = n1 - n0;

    float s0 = 0.f, s1 = 0.f, s2 = 0.f, s3 = 0.f;
    float z0 = 0.f, z1 = 0.f, z2 = 0.f, z3 = 0.f;

    // Stage rowptr span.
    for (int i = t; i <= nn; i += 256) rp[i] = rowptr[n0 + i];
    __syncthreads();
    const int jb0 = rp[0];
    const int tot = rp[nn] - jb0;
    const int stot = (tot < ECAP) ? tot : ECAP;

    // Stage the block's sorted span into LDS (coalesced).
    for (int i = t; i < stot; i += 256) ebuf[i] = sorted[jb0 + i];
    __syncthreads();

    // Each wave: 13 contiguous nodes.
    const int a0n = wv * 13;
    const int b0n = (a0n + 13 < nn) ? a0n + 13 : nn;
    for (int i = a0n; i < b0n; i++) {
        const int jb = rp[i] - jb0;
        const int je = rp[i + 1] - jb0;
        const int elim = (je < stot) ? je : stot;
        float a0 = 0.f, a1 = 0.f, a2 = 0.f, a3 = 0.f;

        // Main: chunks of 16 edges = 4 groups x 4 edges (quarters).
        for (int base = jb; base < elim; base += 16) {
            int2  mm[4];
            float ww[4];
            uint2 vv[4];
            #pragma unroll
            for (int g = 0; g < 4; g++) {
                int idx = base + (g << 2) + q;
                int ci = (idx < elim) ? idx : elim - 1;
                mm[g] = ebuf[ci];
                ww[g] = (idx < elim) ? __uint_as_float(mm[g].y) : 0.0f;
            }
            #pragma unroll
            for (int g = 0; g < 4; g++) {
                vv[g] = *(const uint2*)(support + (((size_t)(unsigned)mm[g].x) << 6) + (fl << 2));
            }
            #pragma unroll
            for (int g = 0; g < 4; g++) {
                a0 = fmaf(ww[g], __uint_as_float(vv[g].x << 16), a0);
                a1 = fmaf(ww[g], __uint_as_float(vv[g].x & 0xFFFF0000u), a1);
                a2 = fmaf(ww[g], __uint_as_float(vv[g].y << 16), a2);
                a3 = fmaf(ww[g], __uint_as_float(vv[g].y & 0xFFFF0000u), a3);
            }
        }

        // Overflow fallback (tot > ECAP, ~never): metadata direct from global.
        const int fb = (jb > elim) ? jb : elim;
        for (int base = fb; base < je; base += 4) {
            int idx = base + q;
            int ci = (idx < je) ? idx : je - 1;
            int2 m = sorted[jb0 + ci];
            float w = (idx < je) ? __uint_as_float(m.y) : 0.0f;
            uint2 v = *(const uint2*)(support + (((size_t)(unsigned)m.x) << 6) + (fl << 2));
            a0 = fmaf(w, __uint_as_float(v.x << 16), a0);
            a1 = fmaf(w, __uint_as_float(v.x & 0xFFFF0000u), a1);
            a2 = fmaf(w, __uint_as_float(v.y << 16), a2);
            a3 = fmaf(w, __uint_as_float(v.y & 0xFFFF0000u), a3);
        }

        // Combine the 4 quarters (each holds the same feature slots).
        a0 += __shfl_xor(a0, 16); a0 += __shfl_xor(a0, 32);
        a1 += __shfl_xor(a1, 16); a1 += __shfl_xor(a1, 32);
        a2 += __shfl_xor(a2, 16); a2 += __shfl_xor(a2, 32);
        a3 += __shfl_xor(a3, 16); a3 += __shfl_xor(a3, 32);

        if (lane < 16) {
            float4 o = make_float4(a0, a1, a2, a3);
            *(float4*)&agg[(size_t)(n0 + i) * NHID + (fl << 2)] = o;
            s0 += a0; s1 += a1; s2 += a2; s3 += a3;
            z0 = fmaf(a0, a0, z0); z1 = fmaf(a1, a1, z1);
            z2 = fmaf(a2, a2, z2); z3 = fmaf(a3, a3, z3);
        }
    }

    if (lane < 16) {
        red[0][wv][(fl << 2) + 0] = s0;
        red[0][wv][(fl << 2) + 1] = s1;
        red[0][wv][(fl << 2) + 2] = s2;
        red[0][wv][(fl << 2) + 3] = s3;
        red[1][wv][(fl << 2) + 0] = z0;
        red[1][wv][(fl << 2) + 1] = z1;
        red[1][wv][(fl << 2) + 2] = z2;
        red[1][wv][(fl << 2) + 3] = z3;
    }
    __syncthreads();
    if (t < 64) {
        atomicAdd(&sums[t], red[0][0][t] + red[0][1][t] + red[0][2][t] + red[0][3][t]);
    } else if (t < 128) {
        int f = t - 64;
        atomicAdd(&sums[64 + f], red[1][0][f] + red[1][1][f] + red[1][2][f] + red[1][3][f]);
    }
}

// ---------------------------------------------------------------------------
// Threefry-2x32, 20 rounds, key=(0,42). Hand-verified vs JAX test vector.
// ---------------------------------------------------------------------------
__device__ __forceinline__ uint32_t rotl32(uint32_t x, int d) {
    return (x << d) | (x >> (32 - d));
}

__device__ __forceinline__ void threefry2x32_0_42(uint32_t x0, uint32_t x1,
                                                  uint32_t& o0, uint32_t& o1) {
    const uint32_t k0 = 0u, k1 = 42u;
    const uint32_t k2 = k0 ^ k1 ^ 0x1BD11BDAu;
    x0 += k0; x1 += k1;
    x0 += x1; x1 = rotl32(x1, 13) ^ x0;
    x0 += x1; x1 = rotl32(x1, 15) ^ x0;
    x0 += x1; x1 = rotl32(x1, 26) ^ x0;
    x0 += x1; x1 = rotl32(x1, 6)  ^ x0;
    x0 += k1; x1 += k2 + 1u;
    x0 += x1; x1 = rotl32(x1, 17) ^ x0;
    x0 += x1; x1 = rotl32(x1, 29) ^ x0;
    x0 += x1; x1 = rotl32(x1, 16) ^ x0;
    x0 += x1; x1 = rotl32(x1, 24) ^ x0;
    x0 += k2; x1 += k0 + 2u;
    x0 += x1; x1 = rotl32(x1, 13) ^ x0;
    x0 += x1; x1 = rotl32(x1, 15) ^ x0;
    x0 += x1; x1 = rotl32(x1, 26) ^ x0;
    x0 += x1; x1 = rotl32(x1, 6)  ^ x0;
    x0 += k0; x1 += k1 + 3u;
    x0 += x1; x1 = rotl32(x1, 17) ^ x0;
    x0 += x1; x1 = rotl32(x1, 29) ^ x0;
    x0 += x1; x1 = rotl32(x1, 16) ^ x0;
    x0 += x1; x1 = rotl32(x1, 24) ^ x0;
    x0 += k1; x1 += k2 + 4u;
    x0 += x1; x1 = rotl32(x1, 13) ^ x0;
    x0 += x1; x1 = rotl32(x1, 15) ^ x0;
    x0 += x1; x1 = rotl32(x1, 26) ^ x0;
    x0 += x1; x1 = rotl32(x1, 6)  ^ x0;
    x0 += k2; x1 += k0 + 5u;
    o0 = x0; o1 = x1;
}

// ---------------------------------------------------------------------------
// Apply (R16): BN affine + ReLU + dropout; finalize fused (scale/shift from
// sums/gamma/beta, all L2-hot). f32 out (overwrites dead support).
// ---------------------------------------------------------------------------
__global__ __launch_bounds__(256) void apply_kernel(const float* __restrict__ agg,
                                                    const float* __restrict__ sums,
                                                    const float* __restrict__ gamma,
                                                    const float* __restrict__ beta,
                                                    float* __restrict__ out) {
    const int i = blockIdx.x * 256 + threadIdx.x;
    if (i >= N_ELEMS) return;
    const int f = i & 63;
    const float inv_n = 1.0f / (float)N_NODES;
    float mean = sums[f] * inv_n;
    float var = sums[64 + f] * inv_n - mean * mean;
    float sc = gamma[f] * rsqrtf(var + 1e-5f);
    float sh = beta[f] - mean * sc;

    uint32_t o0, o1;
    threefry2x32_0_42(0u, (uint32_t)i, o0, o1);
    uint32_t bits = o0 ^ o1;
    float u = __uint_as_float((bits >> 9) | 0x3F800000u) - 1.0f;

    float v = fmaxf(fmaf(agg[i], sc, sh), 0.0f);
    out[i] = (u < 0.7f) ? v * (1.0f / 0.7f) : 0.0f;
}

// ---------------------------------------------------------------------------
extern "C" void kernel_launch(void* const* d_in, const int* in_sizes, int n_in,
                              void* d_out, int out_size, void* d_ws, size_t ws_size,
                              hipStream_t stream) {
    const float* x     = (const float*)d_in[0];
    const int*   row   = (const int*)d_in[1];
    const int*   col   = (const int*)d_in[2];
    const float* ew    = (const float*)d_in[3];
    const float* W     = (const float*)d_in[4];
    const float* gamma = (const float*)d_in[6];
    const float* beta  = (const float*)d_in[7];
    float* out = (float*)d_out;

    float* sums       = (float*)d_ws;                      // 128 f32
    int*   hb         = (int*)(sums + 128);                // 1024 i32 (782 used)
    int*   bbase      = hb + 1024;                         // 1024 i32
    int*   bcur       = bbase + 1024;                      // 1024 i32
    int*   rowptr     = bcur + 1024;                       // 100004 i32
    unsigned short* wt = (unsigned short*)(rowptr + 100004); // 16384 ushort
    float* agg        = (float*)(wt + 16384);              // 6.4M f32
    int2*  sorted     = (int2*)(agg + (size_t)N_ELEMS);    // 1.6M int2
    unsigned short* support = (unsigned short*)out;        // 6.4M bf16, in d_out
    int2*  bucketed   = (int2*)agg;                        // aliases agg (dead)

    // zero sums + hb (adjacent)
    hipMemsetAsync(d_ws, 0, (size_t)(128 + 1024) * 4, stream);

    wtprep_kernel<<<64, 256, 0, stream>>>(W, wt);
    gemm_kernel<<<(N_NODES + 63) / 64, 256, 0, stream>>>(x, wt, support);

    bhist_kernel<<<NBBLK, 256, 0, stream>>>(row, hb);
    bscan_kernel<<<1, 1024, 0, stream>>>(hb, bbase, bcur, rowptr);
    bucket_kernel<<<NBBLK, 256, 0, stream>>>(row, col, ew, bcur, bucketed);
    place_kernel<<<NBUCK, 256, 0, stream>>>(bbase, hb, bucketed, sorted, rowptr);

    gather_kernel<<<GBLK, 256, 0, stream>>>(rowptr, sorted, support, agg, sums);

    apply_kernel<<<(N_ELEMS + 255) / 256, 256, 0, stream>>>(agg, sums, gamma, beta, out);
}

// Round 8
// 311.777 us; speedup vs baseline: 1.1141x; 1.0609x over previous
//
#include <hip/hip_runtime.h>
#include <stdint.h>

#define N_NODES 100000
#define N_EDGES 1600000
#define NFEAT 256
#define NHID 64
#define N_ELEMS (N_NODES * NHID)   // 6,400,000

// R17: slotted buckets (bhist/bscan deleted). 128-row buckets.
#define BSHIFT 7
#define NBUCK 782                  // ceil(100000/128)
#define CHUNK 4096                 // edges per bucket block
#define NBBLK ((N_EDGES + CHUNK - 1) / CHUNK)   // 391
#define CAP 2560                   // slot capacity; mean 2048, sigma ~45 -> +11s

// Gather: block = 64 contiguous nodes (2 blocks per bucket), metadata in LDS.
#define NPB 64
#define GBLK ((N_NODES + NPB - 1) / NPB)        // 1563
#define ECAP 1536                  // LDS edge records; mean 1024, sigma 32 -> +16s

// Config (validated R6/R7): inputs f32, output f32, dropout = JAX partitionable
// threefry (key=(0,42), counter (0,i), bits = o0^o1).
//
// R16 post-mortem: targeted inner-loop fixes to the second tier gave only
//   -8us of a predicted -40..60 -> the ~258us outside gather is spread across
//   9 serial dispatches (launch+ramp+drain) + small dependent passes, not
//   concentrated in the loops touched.
// R17: consolidate. 9 -> 6 dispatches:
//   - slotted buckets: bucket_kernel reserves runs via atomicAdd(&bcnt[b],c)
//     directly (bucketed[b*CAP+...], aliases dead agg; 16MB) -> bhist+bscan
//     deleted (one 6.4MB row pass + a 1-block latency kernel + 2 drains).
//   - place compacts via one atomicAdd(&gcur,nrec) per bucket; bucket order
//     arbitrary, rowptr absolute. Emits bend[b] = base+nrec.
//   - wtprep fused into gemm (W 64KB L2-hot, converted into Bt LDS directly).
//   - gather NPB=64: block spans never cross buckets (2 blocks/bucket);
//     span end for bucket-final blocks comes from bend[b].
//
// ws layout:
//   sums[128] f32 | bcnt[1024] i32 | gcur[32] i32 | bend[1024] i32
//   | rowptr[100004] i32 | agg[6.4M] f32 | sorted[1.6M] int2
// support[6.4M] bf16 staged in d_out (dead before apply overwrites).
// bucketed[NBUCK*CAP] int2 (16.0MB) aliases agg (dead until gather).

typedef __attribute__((ext_vector_type(8))) short bf16x8;
typedef __attribute__((ext_vector_type(4))) float f32x4;

__device__ __forceinline__ unsigned short f2bf(float f) {
    uint32_t u = __float_as_uint(f);
    u += 0x7FFFu + ((u >> 16) & 1u);   // RNE
    return (unsigned short)(u >> 16);
}
__device__ __forceinline__ float bf2f(unsigned short u) {
    return __uint_as_float(((uint32_t)u) << 16);
}

// ---------------------------------------------------------------------------
// GEMM (R17): support[N x 64] = x[N x 256] @ W[256 x 64], bf16 out.
// W conversion fused: each block converts W (f32, L2-hot) into Bt LDS.
// No A staging: lane loads its own 32B of x per kstep, converts in regs.
// ---------------------------------------------------------------------------
__global__ __launch_bounds__(256) void gemm_kernel(const float* __restrict__ x,
                                                   const float* __restrict__ W,
                                                   unsigned short* __restrict__ support) {
    __shared__ unsigned short Bt[64][264];   // Bt[n][k], row stride 528B
    const int t = threadIdx.x;
    const int row0 = blockIdx.x * 64;

    // Fused W^T convert: Bt[n][k] = bf16(W[k*64+n]). Coalesced W reads.
    #pragma unroll
    for (int i = 0; i < 64; i++) {
        int idx = i * 256 + t;
        Bt[idx & 63][idx >> 6] = f2bf(W[idx]);
    }
    __syncthreads();

    const int lane = t & 63;
    const int w = t >> 6;
    const int m = lane & 15;
    const int q = lane >> 4;
    const int growA = row0 + w * 16 + m;
    const int lrow = (growA < N_NODES) ? growA : N_NODES - 1;
    const float* xr = x + (size_t)lrow * NFEAT;

    f32x4 acc0 = {0.f, 0.f, 0.f, 0.f};
    f32x4 acc1 = acc0, acc2 = acc0, acc3 = acc0;

    #pragma unroll
    for (int ks = 0; ks < NFEAT; ks += 32) {
        float4 xa = *(const float4*)&xr[ks + q * 8];
        float4 xb = *(const float4*)&xr[ks + q * 8 + 4];
        ushort4 ua, ub;
        ua.x = f2bf(xa.x); ua.y = f2bf(xa.y); ua.z = f2bf(xa.z); ua.w = f2bf(xa.w);
        ub.x = f2bf(xb.x); ub.y = f2bf(xb.y); ub.z = f2bf(xb.z); ub.w = f2bf(xb.w);
        union { ushort4 u4[2]; bf16x8 v8; } cv;
        cv.u4[0] = ua; cv.u4[1] = ub;
        bf16x8 af = cv.v8;

        bf16x8 b0 = *(const bf16x8*)&Bt[ 0 + m][ks + q * 8];
        bf16x8 b1 = *(const bf16x8*)&Bt[16 + m][ks + q * 8];
        bf16x8 b2 = *(const bf16x8*)&Bt[32 + m][ks + q * 8];
        bf16x8 b3 = *(const bf16x8*)&Bt[48 + m][ks + q * 8];
        acc0 = __builtin_amdgcn_mfma_f32_16x16x32_bf16(af, b0, acc0, 0, 0, 0);
        acc1 = __builtin_amdgcn_mfma_f32_16x16x32_bf16(af, b1, acc1, 0, 0, 0);
        acc2 = __builtin_amdgcn_mfma_f32_16x16x32_bf16(af, b2, acc2, 0, 0, 0);
        acc3 = __builtin_amdgcn_mfma_f32_16x16x32_bf16(af, b3, acc3, 0, 0, 0);
    }

    // C/D layout: row = q*4 + reg, col = nt*16 + m
    #pragma unroll
    for (int reg = 0; reg < 4; reg++) {
        int grow = row0 + w * 16 + q * 4 + reg;
        if (grow < N_NODES) {
            support[(size_t)grow * NHID +  0 + m] = f2bf(acc0[reg]);
            support[(size_t)grow * NHID + 16 + m] = f2bf(acc1[reg]);
            support[(size_t)grow * NHID + 32 + m] = f2bf(acc2[reg]);
            support[(size_t)grow * NHID + 48 + m] = f2bf(acc3[reg]);
        }
    }
}

// ---------------------------------------------------------------------------
// Bucket (R17): scatter edges into 782 slotted row-buckets with LDS
// counting-reorder. Per-(block,bucket) runs reserved directly via
// atomicAdd(&bcnt[b], c) -> base b*CAP+old. Linear sweep writes contiguous.
// ---------------------------------------------------------------------------
__global__ __launch_bounds__(256) void bucket_kernel(const int* __restrict__ row,
                                                     const int* __restrict__ col,
                                                     const float* __restrict__ ew,
                                                     int* __restrict__ bcnt,
                                                     int2* __restrict__ bucketed) {
    __shared__ int2 stage[CHUNK];              // 32 KB
    __shared__ unsigned short bkid[CHUNK];     // 8 KB
    __shared__ int lcnt[1024];                 // 4 KB (782 used)
    __shared__ int lexcl[1024];                // 4 KB
    __shared__ int lbase[1024];                // 4 KB
    __shared__ int p[256];                     // 1 KB
    const int t = threadIdx.x;
    for (int b = t; b < 1024; b += 256) lcnt[b] = 0;
    __syncthreads();

    const int e0 = blockIdx.x * CHUNK;
    const int ctot = (e0 + CHUNK <= N_EDGES) ? CHUNK : (N_EDGES - e0);
    int bk[16];
    int val[16];
    float w[16];
    #pragma unroll
    for (int i = 0; i < 16; i++) {
        int e = e0 + i * 256 + t;
        if (e < N_EDGES) {
            int r = row[e];
            int c = col[e];
            w[i] = ew[e];
            bk[i] = r >> BSHIFT;
            val[i] = ((r & ((1 << BSHIFT) - 1)) << 17) | c;
            atomicAdd(&lcnt[bk[i]], 1);
        } else {
            bk[i] = -1;
        }
    }
    __syncthreads();

    // Block-level exclusive scan of 1024 bucket counts (4 per thread).
    int s0 = lcnt[t * 4 + 0], s1 = lcnt[t * 4 + 1];
    int s2 = lcnt[t * 4 + 2], s3 = lcnt[t * 4 + 3];
    int tsum = s0 + s1 + s2 + s3;
    p[t] = tsum;
    __syncthreads();
    #pragma unroll
    for (int off = 1; off < 256; off <<= 1) {
        int u = (t >= off) ? p[t - off] : 0;
        __syncthreads();
        p[t] += u;
        __syncthreads();
    }
    int pe = p[t] - tsum;
    lexcl[t * 4 + 0] = pe;
    lexcl[t * 4 + 1] = pe + s0;
    lexcl[t * 4 + 2] = pe + s0 + s1;
    lexcl[t * 4 + 3] = pe + s0 + s1 + s2;

    // Reserve global runs in the slotted array; reset lcnt for ranking.
    for (int b = t; b < NBUCK; b += 256) {
        int c = lcnt[b];
        lbase[b] = c ? (b * CAP + atomicAdd(&bcnt[b], c)) : 0;
    }
    __syncthreads();
    for (int b = t; b < 1024; b += 256) lcnt[b] = 0;
    __syncthreads();

    // Rank into LDS stage ordered by bucket.
    #pragma unroll
    for (int i = 0; i < 16; i++) {
        if (bk[i] >= 0) {
            int r = atomicAdd(&lcnt[bk[i]], 1);
            int pos = lexcl[bk[i]] + r;
            stage[pos] = make_int2(val[i], __float_as_int(w[i]));
            bkid[pos] = (unsigned short)bk[i];
        }
    }
    __syncthreads();

    // Linear sweep: consecutive threads -> consecutive global addresses.
    // Slot-overflow guard (p ~ 1e-26): drop writes past the slot end.
    for (int i = t; i < ctot; i += 256) {
        int b = bkid[i];
        int dest = lbase[b] + (i - lexcl[b]);
        if (dest < (b + 1) * CAP) bucketed[dest] = stage[i];
    }
}

// ---------------------------------------------------------------------------
// Place (R17): per-bucket LDS counting sort from slot -> compact sorted.
// Base via one atomicAdd(&gcur, nrec) per bucket (order arbitrary; rowptr
// absolute). Emits rowptr for the bucket's 128 rows + bend[b] = base+nrec.
// ---------------------------------------------------------------------------
__global__ __launch_bounds__(256) void place_kernel(const int* __restrict__ bcnt,
                                                    const int2* __restrict__ bucketed,
                                                    int* __restrict__ gcur,
                                                    int2* __restrict__ sorted,
                                                    int* __restrict__ rowptr,
                                                    int* __restrict__ bend) {
    __shared__ int2 stage[CAP];    // 20KB
    __shared__ int2 stage2[CAP];   // 20KB
    __shared__ int hcnt[128];
    __shared__ int hs[128];
    __shared__ int sbase;
    const int t = threadIdx.x;
    const int b = blockIdx.x;
    int nrec = bcnt[b];
    if (nrec > CAP) nrec = CAP;    // never in practice

    if (t < 128) hcnt[t] = 0;
    if (t == 0) sbase = atomicAdd(gcur, nrec);
    __syncthreads();
    const int bs = sbase;

    for (int i = t; i < nrec; i += 256) {
        int2 rec = bucketed[b * CAP + i];
        stage[i] = rec;
        atomicAdd(&hcnt[rec.x >> 17], 1);
    }
    __syncthreads();

    // Hillis-Steele inclusive scan over 128 counters.
    int v0 = (t < 128) ? hcnt[t] : 0;
    if (t < 128) hs[t] = v0;
    __syncthreads();
    #pragma unroll
    for (int off = 1; off < 128; off <<= 1) {
        int u = (t < 128 && t >= off) ? hs[t - off] : 0;
        __syncthreads();
        if (t < 128) hs[t] += u;
        __syncthreads();
    }
    if (t < 128) {
        int excl = hs[t] - v0;
        int r = (b << BSHIFT) + t;
        if (r < N_NODES) rowptr[r] = bs + excl;
        hcnt[t] = excl;
    }
    if (t == 0) bend[b] = bs + nrec;
    __syncthreads();

    for (int i = t; i < nrec; i += 256) {
        int2 rec = stage[i];
        int lr = rec.x >> 17;
        int pos = atomicAdd(&hcnt[lr], 1);
        stage2[pos] = make_int2(rec.x & 0x1FFFF, rec.y);
    }
    __syncthreads();
    for (int i = t; i < nrec; i += 256) {
        sorted[bs + i] = stage2[i];
    }
}

// ---------------------------------------------------------------------------
// Gather-reduce (R15 core, R17 spans): block = 64 contiguous nodes, all in
// one bucket (2 blocks/bucket) -> sorted span contiguous. Span end for
// bucket-final blocks from bend[b]. Quad-split wave: quarter q handles edge
// (base+g*4+q); lane fl loads uint2 = 4 bf16 features -> one instruction
// gathers 4 edges. Quarter-combine via shfl_xor(16,32); lanes 0..15 store
// float4 row + BN sums.
// ---------------------------------------------------------------------------
__global__ __launch_bounds__(256, 4) void gather_kernel(const int* __restrict__ rowptr,
                                                        const int* __restrict__ bend,
                                                        const int2* __restrict__ sorted,
                                                        const unsigned short* __restrict__ support,
                                                        float* __restrict__ agg,
                                                        float* __restrict__ sums) {
    __shared__ int2 ebuf[ECAP];        // 12 KB
    __shared__ int rp[NPB + 1];
    __shared__ float red[2][4][64];
    const int t = threadIdx.x;
    const int lane = t & 63;
    const int wv = t >> 6;
    const int q = lane >> 4;       // edge quarter
    const int fl = lane & 15;      // feature slot: features [4fl, 4fl+4)
    const int n0 = blockIdx.x * NPB;
    const int n1 = (n0 + NPB < N_NODES) ? n0 + NPB : N_NODES;
    const int nn = n1 - n0;
    const int bkt = n0 >> BSHIFT;

    float s0 = 0.f, s1 = 0.f, s2 = 0.f, s3 = 0.f;
    float z0 = 0.f, z1 = 0.f, z2 = 0.f, z3 = 0.f;

    // Stage rowptr span; rp[nn] = bucket end (bend) for bucket-final blocks.
    for (int i = t; i < nn; i += 256) rp[i] = rowptr[n0 + i];
    if (t == 0) {
        bool bucket_end = (n1 == N_NODES) || ((n1 & ((1 << BSHIFT) - 1)) == 0);
        rp[nn] = bucket_end ? bend[bkt] : rowptr[n1];
    }
    __syncthreads();
    const int jb0 = rp[0];
    const int tot = rp[nn] - jb0;
    const int stot = (tot < ECAP) ? tot : ECAP;

    // Stage the block's sorted span into LDS (coalesced).
    for (int i = t; i < stot; i += 256) ebuf[i] = sorted[jb0 + i];
    __syncthreads();

    // Each wave: 16 contiguous nodes.
    const int a0n = wv * 16;
    const int b0n = (a0n + 16 < nn) ? a0n + 16 : nn;
    for (int i = a0n; i < b0n; i++) {
        const int jb = rp[i] - jb0;
        const int je = rp[i + 1] - jb0;
        const int elim = (je < stot) ? je : stot;
        float a0 = 0.f, a1 = 0.f, a2 = 0.f, a3 = 0.f;

        // Main: chunks of 16 edges = 4 groups x 4 edges (quarters).
        for (int base = jb; base < elim; base += 16) {
            int2  mm[4];
            float ww[4];
            uint2 vv[4];
            #pragma unroll
            for (int g = 0; g < 4; g++) {
                int idx = base + (g << 2) + q;
                int ci = (idx < elim) ? idx : elim - 1;
                mm[g] = ebuf[ci];
                ww[g] = (idx < elim) ? __uint_as_float(mm[g].y) : 0.0f;
            }
            #pragma unroll
            for (int g = 0; g < 4; g++) {
                vv[g] = *(const uint2*)(support + (((size_t)(unsigned)mm[g].x) << 6) + (fl << 2));
            }
            #pragma unroll
            for (int g = 0; g < 4; g++) {
                a0 = fmaf(ww[g], __uint_as_float(vv[g].x << 16), a0);
                a1 = fmaf(ww[g], __uint_as_float(vv[g].x & 0xFFFF0000u), a1);
                a2 = fmaf(ww[g], __uint_as_float(vv[g].y << 16), a2);
                a3 = fmaf(ww[g], __uint_as_float(vv[g].y & 0xFFFF0000u), a3);
            }
        }

        // Overflow fallback (tot > ECAP, ~never): metadata direct from global.
        const int fb = (jb > elim) ? jb : elim;
        for (int base = fb; base < je; base += 4) {
            int idx = base + q;
            int ci = (idx < je) ? idx : je - 1;
            int2 m = sorted[jb0 + ci];
            float w = (idx < je) ? __uint_as_float(m.y) : 0.0f;
            uint2 v = *(const uint2*)(support + (((size_t)(unsigned)m.x) << 6) + (fl << 2));
            a0 = fmaf(w, __uint_as_float(v.x << 16), a0);
            a1 = fmaf(w, __uint_as_float(v.x & 0xFFFF0000u), a1);
            a2 = fmaf(w, __uint_as_float(v.y << 16), a2);
            a3 = fmaf(w, __uint_as_float(v.y & 0xFFFF0000u), a3);
        }

        // Combine the 4 quarters (each holds the same feature slots).
        a0 += __shfl_xor(a0, 16); a0 += __shfl_xor(a0, 32);
        a1 += __shfl_xor(a1, 16); a1 += __shfl_xor(a1, 32);
        a2 += __shfl_xor(a2, 16); a2 += __shfl_xor(a2, 32);
        a3 += __shfl_xor(a3, 16); a3 += __shfl_xor(a3, 32);

        if (lane < 16) {
            float4 o = make_float4(a0, a1, a2, a3);
            *(float4*)&agg[(size_t)(n0 + i) * NHID + (fl << 2)] = o;
            s0 += a0; s1 += a1; s2 += a2; s3 += a3;
            z0 = fmaf(a0, a0, z0); z1 = fmaf(a1, a1, z1);
            z2 = fmaf(a2, a2, z2); z3 = fmaf(a3, a3, z3);
        }
    }

    if (lane < 16) {
        red[0][wv][(fl << 2) + 0] = s0;
        red[0][wv][(fl << 2) + 1] = s1;
        red[0][wv][(fl << 2) + 2] = s2;
        red[0][wv][(fl << 2) + 3] = s3;
        red[1][wv][(fl << 2) + 0] = z0;
        red[1][wv][(fl << 2) + 1] = z1;
        red[1][wv][(fl << 2) + 2] = z2;
        red[1][wv][(fl << 2) + 3] = z3;
    }
    __syncthreads();
    if (t < 64) {
        atomicAdd(&sums[t], red[0][0][t] + red[0][1][t] + red[0][2][t] + red[0][3][t]);
    } else if (t < 128) {
        int f = t - 64;
        atomicAdd(&sums[64 + f], red[1][0][f] + red[1][1][f] + red[1][2][f] + red[1][3][f]);
    }
}

// ---------------------------------------------------------------------------
// Threefry-2x32, 20 rounds, key=(0,42). Hand-verified vs JAX test vector.
// ---------------------------------------------------------------------------
__device__ __forceinline__ uint32_t rotl32(uint32_t x, int d) {
    return (x << d) | (x >> (32 - d));
}

__device__ __forceinline__ void threefry2x32_0_42(uint32_t x0, uint32_t x1,
                                                  uint32_t& o0, uint32_t& o1) {
    const uint32_t k0 = 0u, k1 = 42u;
    const uint32_t k2 = k0 ^ k1 ^ 0x1BD11BDAu;
    x0 += k0; x1 += k1;
    x0 += x1; x1 = rotl32(x1, 13) ^ x0;
    x0 += x1; x1 = rotl32(x1, 15) ^ x0;
    x0 += x1; x1 = rotl32(x1, 26) ^ x0;
    x0 += x1; x1 = rotl32(x1, 6)  ^ x0;
    x0 += k1; x1 += k2 + 1u;
    x0 += x1; x1 = rotl32(x1, 17) ^ x0;
    x0 += x1; x1 = rotl32(x1, 29) ^ x0;
    x0 += x1; x1 = rotl32(x1, 16) ^ x0;
    x0 += x1; x1 = rotl32(x1, 24) ^ x0;
    x0 += k2; x1 += k0 + 2u;
    x0 += x1; x1 = rotl32(x1, 13) ^ x0;
    x0 += x1; x1 = rotl32(x1, 15) ^ x0;
    x0 += x1; x1 = rotl32(x1, 26) ^ x0;
    x0 += x1; x1 = rotl32(x1, 6)  ^ x0;
    x0 += k0; x1 += k1 + 3u;
    x0 += x1; x1 = rotl32(x1, 17) ^ x0;
    x0 += x1; x1 = rotl32(x1, 29) ^ x0;
    x0 += x1; x1 = rotl32(x1, 16) ^ x0;
    x0 += x1; x1 = rotl32(x1, 24) ^ x0;
    x0 += k1; x1 += k2 + 4u;
    x0 += x1; x1 = rotl32(x1, 13) ^ x0;
    x0 += x1; x1 = rotl32(x1, 15) ^ x0;
    x0 += x1; x1 = rotl32(x1, 26) ^ x0;
    x0 += x1; x1 = rotl32(x1, 6)  ^ x0;
    x0 += k2; x1 += k0 + 5u;
    o0 = x0; o1 = x1;
}

// ---------------------------------------------------------------------------
// Apply: BN affine + ReLU + dropout; finalize fused (scale/shift from sums).
// ---------------------------------------------------------------------------
__global__ __launch_bounds__(256) void apply_kernel(const float* __restrict__ agg,
                                                    const float* __restrict__ sums,
                                                    const float* __restrict__ gamma,
                                                    const float* __restrict__ beta,
                                                    float* __restrict__ out) {
    const int i = blockIdx.x * 256 + threadIdx.x;
    if (i >= N_ELEMS) return;
    const int f = i & 63;
    const float inv_n = 1.0f / (float)N_NODES;
    float mean = sums[f] * inv_n;
    float var = sums[64 + f] * inv_n - mean * mean;
    float sc = gamma[f] * rsqrtf(var + 1e-5f);
    float sh = beta[f] - mean * sc;

    uint32_t o0, o1;
    threefry2x32_0_42(0u, (uint32_t)i, o0, o1);
    uint32_t bits = o0 ^ o1;
    float u = __uint_as_float((bits >> 9) | 0x3F800000u) - 1.0f;

    float v = fmaxf(fmaf(agg[i], sc, sh), 0.0f);
    out[i] = (u < 0.7f) ? v * (1.0f / 0.7f) : 0.0f;
}

// ---------------------------------------------------------------------------
extern "C" void kernel_launch(void* const* d_in, const int* in_sizes, int n_in,
                              void* d_out, int out_size, void* d_ws, size_t ws_size,
                              hipStream_t stream) {
    const float* x     = (const float*)d_in[0];
    const int*   row   = (const int*)d_in[1];
    const int*   col   = (const int*)d_in[2];
    const float* ew    = (const float*)d_in[3];
    const float* W     = (const float*)d_in[4];
    const float* gamma = (const float*)d_in[6];
    const float* beta  = (const float*)d_in[7];
    float* out = (float*)d_out;

    float* sums       = (float*)d_ws;                      // 128 f32
    int*   bcnt       = (int*)(sums + 128);                // 1024 i32 (782 used)
    int*   gcur       = bcnt + 1024;                       // 32 i32 ([0] used)
    int*   bend       = gcur + 32;                         // 1024 i32
    int*   rowptr     = bend + 1024;                       // 100004 i32
    float* agg        = (float*)(rowptr + 100004);         // 6.4M f32
    int2*  sorted     = (int2*)(agg + (size_t)N_ELEMS);    // 1.6M int2
    unsigned short* support = (unsigned short*)out;        // 6.4M bf16, in d_out
    int2*  bucketed   = (int2*)agg;                        // [NBUCK*CAP] aliases agg

    // zero sums + bcnt + gcur (contiguous)
    hipMemsetAsync(d_ws, 0, (size_t)(128 + 1024 + 32) * 4, stream);

    gemm_kernel<<<(N_NODES + 63) / 64, 256, 0, stream>>>(x, W, support);
    bucket_kernel<<<NBBLK, 256, 0, stream>>>(row, col, ew, bcnt, bucketed);
    place_kernel<<<NBUCK, 256, 0, stream>>>(bcnt, bucketed, gcur, sorted, rowptr, bend);
    gather_kernel<<<GBLK, 256, 0, stream>>>(rowptr, bend, sorted, support, agg, sums);
    apply_kernel<<<(N_ELEMS + 255) / 256, 256, 0, stream>>>(agg, sums, gamma, beta, out);
}

// Round 9
// 273.925 us; speedup vs baseline: 1.2680x; 1.1382x over previous
//
#include <hip/hip_runtime.h>
#include <stdint.h>

#define N_NODES 100000
#define N_EDGES 1600000
#define NFEAT 256
#define NHID 64
#define N_ELEMS (N_NODES * NHID)   // 6,400,000

// R17/R18: slotted row-buckets of 128 rows.
#define BSHIFT 7
#define NBUCK 782                  // ceil(100000/128)
#define CHUNK 4096                 // edges per bucket block
#define NBBLK ((N_EDGES + CHUNK - 1) / CHUNK)   // 391
#define CAP 2560                   // records staged/sorted; mean 2048 +11sigma
#define SLOTSZ 4096                // slot stride (records) = 32KB = agg rows of bucket

// Config (validated R6/R7): inputs f32, output f32, dropout = JAX partitionable
// threefry (key=(0,42), counter (0,i), bits = o0^o1).
//
// R17 post-mortem: consolidation 9->6 dispatches = -19us (330.8->311.8);
//   gather 66.5us. Non-gather residual ~245us = gemm+bucket+place+apply+
//   memset+drains. R16 lesson: remove passes, don't tune loops.
// R18: fuse place INTO gather (placegather). place's stage2 (sorted bucket)
//   already lives in LDS in the exact layout gather consumes -> sort in LDS,
//   gather directly from it. sorted/rowptr/bend/gcur + ebuf restage deleted.
//   Alias safety: slot stride re-set to 4096 records (32KB) so bucket b's
//   slots occupy exactly agg rows b*128..b*128+127 -> block b reads only the
//   region it later overwrites; no cross-block alias race.
//   512 threads (8 waves x 16 nodes, same nodes/wave as R17); LDS ~26KB
//   (first stage buffer dropped: hist+rank passes each read global slots,
//   2nd read L2-warm).
// Pipeline: memset -> gemm -> bucket -> placegather -> apply.
//
// ws layout:
//   sums[128] f32 | bcnt[1024] i32 | agg[NBUCK*SLOTSZ*8 B = 25.62MB]
// support[6.4M] bf16 staged in d_out (dead before apply overwrites).
// bucketed aliases agg with per-bucket 32KB slots.

typedef __attribute__((ext_vector_type(8))) short bf16x8;
typedef __attribute__((ext_vector_type(4))) float f32x4;

__device__ __forceinline__ unsigned short f2bf(float f) {
    uint32_t u = __float_as_uint(f);
    u += 0x7FFFu + ((u >> 16) & 1u);   // RNE
    return (unsigned short)(u >> 16);
}
__device__ __forceinline__ float bf2f(unsigned short u) {
    return __uint_as_float(((uint32_t)u) << 16);
}

// ---------------------------------------------------------------------------
// GEMM: support[N x 64] = x[N x 256] @ W[256 x 64], bf16 out.
// W conversion fused (W 64KB, L2-hot). No A staging: lane loads its own 32B
// of x per kstep, converts in regs, MFMA direct.
// ---------------------------------------------------------------------------
__global__ __launch_bounds__(256) void gemm_kernel(const float* __restrict__ x,
                                                   const float* __restrict__ W,
                                                   unsigned short* __restrict__ support) {
    __shared__ unsigned short Bt[64][264];   // Bt[n][k], row stride 528B
    const int t = threadIdx.x;
    const int row0 = blockIdx.x * 64;

    #pragma unroll
    for (int i = 0; i < 64; i++) {
        int idx = i * 256 + t;
        Bt[idx & 63][idx >> 6] = f2bf(W[idx]);
    }
    __syncthreads();

    const int lane = t & 63;
    const int w = t >> 6;
    const int m = lane & 15;
    const int q = lane >> 4;
    const int growA = row0 + w * 16 + m;
    const int lrow = (growA < N_NODES) ? growA : N_NODES - 1;
    const float* xr = x + (size_t)lrow * NFEAT;

    f32x4 acc0 = {0.f, 0.f, 0.f, 0.f};
    f32x4 acc1 = acc0, acc2 = acc0, acc3 = acc0;

    #pragma unroll
    for (int ks = 0; ks < NFEAT; ks += 32) {
        float4 xa = *(const float4*)&xr[ks + q * 8];
        float4 xb = *(const float4*)&xr[ks + q * 8 + 4];
        ushort4 ua, ub;
        ua.x = f2bf(xa.x); ua.y = f2bf(xa.y); ua.z = f2bf(xa.z); ua.w = f2bf(xa.w);
        ub.x = f2bf(xb.x); ub.y = f2bf(xb.y); ub.z = f2bf(xb.z); ub.w = f2bf(xb.w);
        union { ushort4 u4[2]; bf16x8 v8; } cv;
        cv.u4[0] = ua; cv.u4[1] = ub;
        bf16x8 af = cv.v8;

        bf16x8 b0 = *(const bf16x8*)&Bt[ 0 + m][ks + q * 8];
        bf16x8 b1 = *(const bf16x8*)&Bt[16 + m][ks + q * 8];
        bf16x8 b2 = *(const bf16x8*)&Bt[32 + m][ks + q * 8];
        bf16x8 b3 = *(const bf16x8*)&Bt[48 + m][ks + q * 8];
        acc0 = __builtin_amdgcn_mfma_f32_16x16x32_bf16(af, b0, acc0, 0, 0, 0);
        acc1 = __builtin_amdgcn_mfma_f32_16x16x32_bf16(af, b1, acc1, 0, 0, 0);
        acc2 = __builtin_amdgcn_mfma_f32_16x16x32_bf16(af, b2, acc2, 0, 0, 0);
        acc3 = __builtin_amdgcn_mfma_f32_16x16x32_bf16(af, b3, acc3, 0, 0, 0);
    }

    #pragma unroll
    for (int reg = 0; reg < 4; reg++) {
        int grow = row0 + w * 16 + q * 4 + reg;
        if (grow < N_NODES) {
            support[(size_t)grow * NHID +  0 + m] = f2bf(acc0[reg]);
            support[(size_t)grow * NHID + 16 + m] = f2bf(acc1[reg]);
            support[(size_t)grow * NHID + 32 + m] = f2bf(acc2[reg]);
            support[(size_t)grow * NHID + 48 + m] = f2bf(acc3[reg]);
        }
    }
}

// ---------------------------------------------------------------------------
// Bucket: scatter edges into 782 slotted row-buckets with LDS counting-
// reorder. Per-(block,bucket) runs reserved via atomicAdd(&bcnt[b], c);
// slot base = b*SLOTSZ. Linear sweep writes contiguous runs.
// ---------------------------------------------------------------------------
__global__ __launch_bounds__(256) void bucket_kernel(const int* __restrict__ row,
                                                     const int* __restrict__ col,
                                                     const float* __restrict__ ew,
                                                     int* __restrict__ bcnt,
                                                     int2* __restrict__ bucketed) {
    __shared__ int2 stage[CHUNK];              // 32 KB
    __shared__ unsigned short bkid[CHUNK];     // 8 KB
    __shared__ int lcnt[1024];                 // 4 KB (782 used)
    __shared__ int lexcl[1024];                // 4 KB
    __shared__ int lbase[1024];                // 4 KB
    __shared__ int p[256];                     // 1 KB
    const int t = threadIdx.x;
    for (int b = t; b < 1024; b += 256) lcnt[b] = 0;
    __syncthreads();

    const int e0 = blockIdx.x * CHUNK;
    const int ctot = (e0 + CHUNK <= N_EDGES) ? CHUNK : (N_EDGES - e0);
    int bk[16];
    int val[16];
    float w[16];
    #pragma unroll
    for (int i = 0; i < 16; i++) {
        int e = e0 + i * 256 + t;
        if (e < N_EDGES) {
            int r = row[e];
            int c = col[e];
            w[i] = ew[e];
            bk[i] = r >> BSHIFT;
            val[i] = ((r & ((1 << BSHIFT) - 1)) << 17) | c;
            atomicAdd(&lcnt[bk[i]], 1);
        } else {
            bk[i] = -1;
        }
    }
    __syncthreads();

    // Block-level exclusive scan of 1024 bucket counts (4 per thread).
    int s0 = lcnt[t * 4 + 0], s1 = lcnt[t * 4 + 1];
    int s2 = lcnt[t * 4 + 2], s3 = lcnt[t * 4 + 3];
    int tsum = s0 + s1 + s2 + s3;
    p[t] = tsum;
    __syncthreads();
    #pragma unroll
    for (int off = 1; off < 256; off <<= 1) {
        int u = (t >= off) ? p[t - off] : 0;
        __syncthreads();
        p[t] += u;
        __syncthreads();
    }
    int pe = p[t] - tsum;
    lexcl[t * 4 + 0] = pe;
    lexcl[t * 4 + 1] = pe + s0;
    lexcl[t * 4 + 2] = pe + s0 + s1;
    lexcl[t * 4 + 3] = pe + s0 + s1 + s2;

    // Reserve slot runs; reset lcnt for ranking.
    for (int b = t; b < NBUCK; b += 256) {
        int c = lcnt[b];
        lbase[b] = c ? (b * SLOTSZ + atomicAdd(&bcnt[b], c)) : 0;
    }
    __syncthreads();
    for (int b = t; b < 1024; b += 256) lcnt[b] = 0;
    __syncthreads();

    // Rank into LDS stage ordered by bucket.
    #pragma unroll
    for (int i = 0; i < 16; i++) {
        if (bk[i] >= 0) {
            int r = atomicAdd(&lcnt[bk[i]], 1);
            int pos = lexcl[bk[i]] + r;
            stage[pos] = make_int2(val[i], __float_as_int(w[i]));
            bkid[pos] = (unsigned short)bk[i];
        }
    }
    __syncthreads();

    // Linear sweep; slot-overflow guard (drop past CAP; p ~ 1e-26).
    for (int i = t; i < ctot; i += 256) {
        int b = bkid[i];
        int dest = lbase[b] + (i - lexcl[b]);
        if (dest < b * SLOTSZ + CAP) bucketed[dest] = stage[i];
    }
}

// ---------------------------------------------------------------------------
// PlaceGather (R18): one block per bucket. Phase 1: hist slot records ->
// scan -> rank into LDS stage2 (counting sort; rank pass re-reads L2-warm
// slots). Phase 2: gather straight from stage2 (R15 quad-split inner loop),
// write agg rows (exactly the region this bucket's slots occupied), fused
// BN partial sums. 512 threads = 8 waves x 16 nodes.
// ---------------------------------------------------------------------------
__global__ __launch_bounds__(512) void placegather_kernel(const int* __restrict__ bcnt,
                                                          const int2* __restrict__ bucketed,
                                                          const unsigned short* __restrict__ support,
                                                          float* __restrict__ agg,
                                                          float* __restrict__ sums) {
    __shared__ int2 stage2[CAP];       // 20 KB (sorted bucket records)
    __shared__ int hcnt[128];
    __shared__ int sv[128];
    __shared__ int hexcl[129];
    __shared__ float red[2][8][64];    // 4 KB
    const int t = threadIdx.x;
    const int lane = t & 63;
    const int wv = t >> 6;
    const int q = lane >> 4;       // edge quarter
    const int fl = lane & 15;      // feature slot: features [4fl, 4fl+4)
    const int b = blockIdx.x;
    int nrec = bcnt[b];
    if (nrec > CAP) nrec = CAP;    // consistent with bucket guard

    if (t < 128) hcnt[t] = 0;
    __syncthreads();

    // Phase 1a: histogram local rows.
    for (int i = t; i < nrec; i += 512) {
        int2 rec = bucketed[b * SLOTSZ + i];
        atomicAdd(&hcnt[rec.x >> 17], 1);
    }
    __syncthreads();

    // Phase 1b: scan 128 counts -> exclusive offsets.
    int v0 = (t < 128) ? hcnt[t] : 0;
    if (t < 128) sv[t] = v0;
    __syncthreads();
    #pragma unroll
    for (int off = 1; off < 128; off <<= 1) {
        int u = (t < 128 && t >= off) ? sv[t - off] : 0;
        __syncthreads();
        if (t < 128) sv[t] += u;
        __syncthreads();
    }
    if (t < 128) {
        int excl = sv[t] - v0;
        hexcl[t] = excl;
        hcnt[t] = excl;            // running cursor
        if (t == 127) hexcl[128] = sv[127];
    }
    __syncthreads();

    // Phase 1c: rank-scatter into sorted LDS (re-read slots, L2-warm).
    for (int i = t; i < nrec; i += 512) {
        int2 rec = bucketed[b * SLOTSZ + i];
        int lr = rec.x >> 17;
        int pos = atomicAdd(&hcnt[lr], 1);
        stage2[pos] = make_int2(rec.x & 0x1FFFF, rec.y);
    }
    __syncthreads();

    // Phase 2: gather. Wave wv handles local rows [wv*16, wv*16+16).
    float s0 = 0.f, s1 = 0.f, s2 = 0.f, s3 = 0.f;
    float z0 = 0.f, z1 = 0.f, z2 = 0.f, z3 = 0.f;

    for (int i = wv * 16; i < wv * 16 + 16; i++) {
        const int jb = hexcl[i];
        const int je = hexcl[i + 1];
        float a0 = 0.f, a1 = 0.f, a2 = 0.f, a3 = 0.f;

        for (int base = jb; base < je; base += 16) {
            int2  mm[4];
            float ww[4];
            uint2 vv[4];
            #pragma unroll
            for (int g = 0; g < 4; g++) {
                int idx = base + (g << 2) + q;
                int ci = (idx < je) ? idx : je - 1;   // je > jb in this loop
                mm[g] = stage2[ci];
                ww[g] = (idx < je) ? __uint_as_float(mm[g].y) : 0.0f;
            }
            #pragma unroll
            for (int g = 0; g < 4; g++) {
                vv[g] = *(const uint2*)(support + (((size_t)(unsigned)mm[g].x) << 6) + (fl << 2));
            }
            #pragma unroll
            for (int g = 0; g < 4; g++) {
                a0 = fmaf(ww[g], __uint_as_float(vv[g].x << 16), a0);
                a1 = fmaf(ww[g], __uint_as_float(vv[g].x & 0xFFFF0000u), a1);
                a2 = fmaf(ww[g], __uint_as_float(vv[g].y << 16), a2);
                a3 = fmaf(ww[g], __uint_as_float(vv[g].y & 0xFFFF0000u), a3);
            }
        }

        // Combine the 4 quarters.
        a0 += __shfl_xor(a0, 16); a0 += __shfl_xor(a0, 32);
        a1 += __shfl_xor(a1, 16); a1 += __shfl_xor(a1, 32);
        a2 += __shfl_xor(a2, 16); a2 += __shfl_xor(a2, 32);
        a3 += __shfl_xor(a3, 16); a3 += __shfl_xor(a3, 32);

        int r = (b << BSHIFT) + i;
        if (lane < 16 && r < N_NODES) {
            float4 o = make_float4(a0, a1, a2, a3);
            *(float4*)&agg[(size_t)r * NHID + (fl << 2)] = o;
            s0 += a0; s1 += a1; s2 += a2; s3 += a3;
            z0 = fmaf(a0, a0, z0); z1 = fmaf(a1, a1, z1);
            z2 = fmaf(a2, a2, z2); z3 = fmaf(a3, a3, z3);
        }
    }

    if (lane < 16) {
        red[0][wv][(fl << 2) + 0] = s0;
        red[0][wv][(fl << 2) + 1] = s1;
        red[0][wv][(fl << 2) + 2] = s2;
        red[0][wv][(fl << 2) + 3] = s3;
        red[1][wv][(fl << 2) + 0] = z0;
        red[1][wv][(fl << 2) + 1] = z1;
        red[1][wv][(fl << 2) + 2] = z2;
        red[1][wv][(fl << 2) + 3] = z3;
    }
    __syncthreads();
    if (t < 64) {
        float acc = 0.f;
        #pragma unroll
        for (int k = 0; k < 8; k++) acc += red[0][k][t];
        atomicAdd(&sums[t], acc);
    } else if (t < 128) {
        int f = t - 64;
        float acc = 0.f;
        #pragma unroll
        for (int k = 0; k < 8; k++) acc += red[1][k][f];
        atomicAdd(&sums[64 + f], acc);
    }
}

// ---------------------------------------------------------------------------
// Threefry-2x32, 20 rounds, key=(0,42). Hand-verified vs JAX test vector.
// ---------------------------------------------------------------------------
__device__ __forceinline__ uint32_t rotl32(uint32_t x, int d) {
    return (x << d) | (x >> (32 - d));
}

__device__ __forceinline__ void threefry2x32_0_42(uint32_t x0, uint32_t x1,
                                                  uint32_t& o0, uint32_t& o1) {
    const uint32_t k0 = 0u, k1 = 42u;
    const uint32_t k2 = k0 ^ k1 ^ 0x1BD11BDAu;
    x0 += k0; x1 += k1;
    x0 += x1; x1 = rotl32(x1, 13) ^ x0;
    x0 += x1; x1 = rotl32(x1, 15) ^ x0;
    x0 += x1; x1 = rotl32(x1, 26) ^ x0;
    x0 += x1; x1 = rotl32(x1, 6)  ^ x0;
    x0 += k1; x1 += k2 + 1u;
    x0 += x1; x1 = rotl32(x1, 17) ^ x0;
    x0 += x1; x1 = rotl32(x1, 29) ^ x0;
    x0 += x1; x1 = rotl32(x1, 16) ^ x0;
    x0 += x1; x1 = rotl32(x1, 24) ^ x0;
    x0 += k2; x1 += k0 + 2u;
    x0 += x1; x1 = rotl32(x1, 13) ^ x0;
    x0 += x1; x1 = rotl32(x1, 15) ^ x0;
    x0 += x1; x1 = rotl32(x1, 26) ^ x0;
    x0 += x1; x1 = rotl32(x1, 6)  ^ x0;
    x0 += k0; x1 += k1 + 3u;
    x0 += x1; x1 = rotl32(x1, 17) ^ x0;
    x0 += x1; x1 = rotl32(x1, 29) ^ x0;
    x0 += x1; x1 = rotl32(x1, 16) ^ x0;
    x0 += x1; x1 = rotl32(x1, 24) ^ x0;
    x0 += k1; x1 += k2 + 4u;
    x0 += x1; x1 = rotl32(x1, 13) ^ x0;
    x0 += x1; x1 = rotl32(x1, 15) ^ x0;
    x0 += x1; x1 = rotl32(x1, 26) ^ x0;
    x0 += x1; x1 = rotl32(x1, 6)  ^ x0;
    x0 += k2; x1 += k0 + 5u;
    o0 = x0; o1 = x1;
}

// ---------------------------------------------------------------------------
// Apply: BN affine + ReLU + dropout; finalize fused (scale/shift from sums).
// ---------------------------------------------------------------------------
__global__ __launch_bounds__(256) void apply_kernel(const float* __restrict__ agg,
                                                    const float* __restrict__ sums,
                                                    const float* __restrict__ gamma,
                                                    const float* __restrict__ beta,
                                                    float* __restrict__ out) {
    const int i = blockIdx.x * 256 + threadIdx.x;
    if (i >= N_ELEMS) return;
    const int f = i & 63;
    const float inv_n = 1.0f / (float)N_NODES;
    float mean = sums[f] * inv_n;
    float var = sums[64 + f] * inv_n - mean * mean;
    float sc = gamma[f] * rsqrtf(var + 1e-5f);
    float sh = beta[f] - mean * sc;

    uint32_t o0, o1;
    threefry2x32_0_42(0u, (uint32_t)i, o0, o1);
    uint32_t bits = o0 ^ o1;
    float u = __uint_as_float((bits >> 9) | 0x3F800000u) - 1.0f;

    float v = fmaxf(fmaf(agg[i], sc, sh), 0.0f);
    out[i] = (u < 0.7f) ? v * (1.0f / 0.7f) : 0.0f;
}

// ---------------------------------------------------------------------------
extern "C" void kernel_launch(void* const* d_in, const int* in_sizes, int n_in,
                              void* d_out, int out_size, void* d_ws, size_t ws_size,
                              hipStream_t stream) {
    const float* x     = (const float*)d_in[0];
    const int*   row   = (const int*)d_in[1];
    const int*   col   = (const int*)d_in[2];
    const float* ew    = (const float*)d_in[3];
    const float* W     = (const float*)d_in[4];
    const float* gamma = (const float*)d_in[6];
    const float* beta  = (const float*)d_in[7];
    float* out = (float*)d_out;

    float* sums       = (float*)d_ws;                      // 128 f32
    int*   bcnt       = (int*)(sums + 128);                // 1024 i32 (782 used)
    float* agg        = (float*)(bcnt + 1024);             // 25.62 MB (NBUCK*SLOTSZ*8)
    unsigned short* support = (unsigned short*)out;        // 6.4M bf16, in d_out
    int2*  bucketed   = (int2*)agg;                        // slotted, stride SLOTSZ

    // zero sums + bcnt (contiguous)
    hipMemsetAsync(d_ws, 0, (size_t)(128 + 1024) * 4, stream);

    gemm_kernel<<<(N_NODES + 63) / 64, 256, 0, stream>>>(x, W, support);
    bucket_kernel<<<NBBLK, 256, 0, stream>>>(row, col, ew, bcnt, bucketed);
    placegather_kernel<<<NBUCK, 512, 0, stream>>>(bcnt, bucketed, support, agg, sums);
    apply_kernel<<<(N_ELEMS + 255) / 256, 256, 0, stream>>>(agg, sums, gamma, beta, out);
}

// Round 11
// 266.280 us; speedup vs baseline: 1.3044x; 1.0287x over previous
//
#include <hip/hip_runtime.h>
#include <stdint.h>

#define N_NODES 100000
#define N_EDGES 1600000
#define NFEAT 256
#define NHID 64
#define N_ELEMS (N_NODES * NHID)   // 6,400,000

// Slotted row-buckets of 128 rows.
#define BSHIFT 7
#define NBUCK 782                  // ceil(100000/128)
#define CHUNK 4096                 // edges per bucket block
#define NBBLK ((N_EDGES + CHUNK - 1) / CHUNK)   // 391
#define CAP 2560                   // records staged/sorted; mean 2048 +11sigma
#define SLOTSZ 4096                // slot stride (records) = 32KB = agg rows of bucket

// R19: gemm+bucket fused, role-interleaved (every 5th block = bucket).
#define GB_TOTAL 1955              // 1564 gemm-slots (1563 used) + 391 bucket
#define GB_LDS 53248               // bucket layout: 32K stage + 8K bkid + 3x4K (p overlaid)

// Config (validated R6/R7): inputs f32, output f32, dropout = JAX partitionable
// threefry (key=(0,42), counter (0,i), bits = o0^o1).
//
// R18 post-mortem: 311.8 -> 273.9us. Top-5 now = harness 400MB ws-repoison
//   fills (59.6us) -> every pipeline kernel < 59us; no dominant kernel left.
// R19: overlap the independent producers. gemm and bucket share no data ->
//   one grid-partitioned kernel, roles interleaved by blockIdx (bid%5==4 =
//   bucket) so both kinds are co-resident immediately -> runtime ~ max not
//   sum. Dynamic LDS 52KB. apply vectorized float4/thread.
//   Rerun: R19 bench was an infra failure (container acquire), not a kernel
//   verdict. Hardened placegather hcnt indexing (lr & 127) to remove the
//   only OOB path (unwritten-slot garbage if a bucket ever exceeded CAP).
// Pipeline: memset -> gemm_bucket -> placegather -> apply.
//
// ws layout:
//   sums[128] f32 | bcnt[1024] i32 | agg[NBUCK*SLOTSZ*8 B = 25.62MB]
// support[6.4M] bf16 staged in d_out (dead before apply overwrites).
// bucketed aliases agg with per-bucket 32KB slots (SLOTSZ records).

typedef __attribute__((ext_vector_type(8))) short bf16x8;
typedef __attribute__((ext_vector_type(4))) float f32x4;

__device__ __forceinline__ unsigned short f2bf(float f) {
    uint32_t u = __float_as_uint(f);
    u += 0x7FFFu + ((u >> 16) & 1u);   // RNE
    return (unsigned short)(u >> 16);
}
__device__ __forceinline__ float bf2f(unsigned short u) {
    return __uint_as_float(((uint32_t)u) << 16);
}

// ---------------------------------------------------------------------------
// Fused GEMM | Bucket (R19). Role by blockIdx: bid%5==4 -> bucket block
// (bucket_id = bid/5, 391 total); else gemm block (gemm_id = (bid/5)*4 +
// bid%5, 0..1563; 1563 used). Dynamic LDS, per-role layout.
//
// GEMM: support[N x 64] = x[N x 256] @ W[256 x 64], bf16 out. W conversion
// fused (64KB, L2-hot). No A staging: lane loads own 32B of x per kstep.
// Bucket: LDS counting-reorder scatter into slotted buckets; contiguous runs.
// ---------------------------------------------------------------------------
__global__ __launch_bounds__(256) void gemm_bucket_kernel(const float* __restrict__ x,
                                                          const float* __restrict__ W,
                                                          unsigned short* __restrict__ support,
                                                          const int* __restrict__ row,
                                                          const int* __restrict__ col,
                                                          const float* __restrict__ ew,
                                                          int* __restrict__ bcnt,
                                                          int2* __restrict__ bucketed) {
    extern __shared__ char smem[];
    const int t = threadIdx.x;
    const int bid = blockIdx.x;

    if ((bid % 5) != 4) {
        // ---------------- GEMM role ----------------
        const int gemm_id = (bid / 5) * 4 + (bid % 5);
        const int row0 = gemm_id * 64;
        if (row0 >= N_NODES) return;

        unsigned short (*Bt)[264] = (unsigned short (*)[264])smem;  // 33.8 KB

        #pragma unroll
        for (int i = 0; i < 64; i++) {
            int idx = i * 256 + t;
            Bt[idx & 63][idx >> 6] = f2bf(W[idx]);
        }
        __syncthreads();

        const int lane = t & 63;
        const int w = t >> 6;
        const int m = lane & 15;
        const int q = lane >> 4;
        const int growA = row0 + w * 16 + m;
        const int lrow = (growA < N_NODES) ? growA : N_NODES - 1;
        const float* xr = x + (size_t)lrow * NFEAT;

        f32x4 acc0 = {0.f, 0.f, 0.f, 0.f};
        f32x4 acc1 = acc0, acc2 = acc0, acc3 = acc0;

        #pragma unroll
        for (int ks = 0; ks < NFEAT; ks += 32) {
            float4 xa = *(const float4*)&xr[ks + q * 8];
            float4 xb = *(const float4*)&xr[ks + q * 8 + 4];
            ushort4 ua, ub;
            ua.x = f2bf(xa.x); ua.y = f2bf(xa.y); ua.z = f2bf(xa.z); ua.w = f2bf(xa.w);
            ub.x = f2bf(xb.x); ub.y = f2bf(xb.y); ub.z = f2bf(xb.z); ub.w = f2bf(xb.w);
            union { ushort4 u4[2]; bf16x8 v8; } cv;
            cv.u4[0] = ua; cv.u4[1] = ub;
            bf16x8 af = cv.v8;

            bf16x8 b0 = *(const bf16x8*)&Bt[ 0 + m][ks + q * 8];
            bf16x8 b1 = *(const bf16x8*)&Bt[16 + m][ks + q * 8];
            bf16x8 b2 = *(const bf16x8*)&Bt[32 + m][ks + q * 8];
            bf16x8 b3 = *(const bf16x8*)&Bt[48 + m][ks + q * 8];
            acc0 = __builtin_amdgcn_mfma_f32_16x16x32_bf16(af, b0, acc0, 0, 0, 0);
            acc1 = __builtin_amdgcn_mfma_f32_16x16x32_bf16(af, b1, acc1, 0, 0, 0);
            acc2 = __builtin_amdgcn_mfma_f32_16x16x32_bf16(af, b2, acc2, 0, 0, 0);
            acc3 = __builtin_amdgcn_mfma_f32_16x16x32_bf16(af, b3, acc3, 0, 0, 0);
        }

        #pragma unroll
        for (int reg = 0; reg < 4; reg++) {
            int grow = row0 + w * 16 + q * 4 + reg;
            if (grow < N_NODES) {
                support[(size_t)grow * NHID +  0 + m] = f2bf(acc0[reg]);
                support[(size_t)grow * NHID + 16 + m] = f2bf(acc1[reg]);
                support[(size_t)grow * NHID + 32 + m] = f2bf(acc2[reg]);
                support[(size_t)grow * NHID + 48 + m] = f2bf(acc3[reg]);
            }
        }
    } else {
        // ---------------- Bucket role ----------------
        const int bblk = bid / 5;                              // 0..390
        int2* stage = (int2*)smem;                             // 32 KB
        unsigned short* bkid = (unsigned short*)(smem + 32768); // 8 KB
        int* lcnt  = (int*)(smem + 40960);                     // 4 KB
        int* lexcl = (int*)(smem + 45056);                     // 4 KB
        int* lbase = (int*)(smem + 49152);                     // 4 KB
        int* p     = lbase;                                    // overlays lbase

        for (int b = t; b < 1024; b += 256) lcnt[b] = 0;
        __syncthreads();

        const int e0 = bblk * CHUNK;
        const int ctot = (e0 + CHUNK <= N_EDGES) ? CHUNK : (N_EDGES - e0);
        int bk[16];
        int val[16];
        float w[16];
        #pragma unroll
        for (int i = 0; i < 16; i++) {
            int e = e0 + i * 256 + t;
            if (e < N_EDGES) {
                int r = row[e];
                int c = col[e];
                w[i] = ew[e];
                bk[i] = r >> BSHIFT;
                val[i] = ((r & ((1 << BSHIFT) - 1)) << 17) | c;
                atomicAdd(&lcnt[bk[i]], 1);
            } else {
                bk[i] = -1;
            }
        }
        __syncthreads();

        // Block-level exclusive scan of 1024 bucket counts (4 per thread).
        int s0 = lcnt[t * 4 + 0], s1 = lcnt[t * 4 + 1];
        int s2 = lcnt[t * 4 + 2], s3 = lcnt[t * 4 + 3];
        int tsum = s0 + s1 + s2 + s3;
        p[t] = tsum;
        __syncthreads();
        #pragma unroll
        for (int off = 1; off < 256; off <<= 1) {
            int u = (t >= off) ? p[t - off] : 0;
            __syncthreads();
            p[t] += u;
            __syncthreads();
        }
        int pe = p[t] - tsum;
        __syncthreads();   // p reads done before lbase overwrites
        lexcl[t * 4 + 0] = pe;
        lexcl[t * 4 + 1] = pe + s0;
        lexcl[t * 4 + 2] = pe + s0 + s1;
        lexcl[t * 4 + 3] = pe + s0 + s1 + s2;

        // Reserve slot runs; reset lcnt for ranking.
        for (int b = t; b < NBUCK; b += 256) {
            int c = lcnt[b];
            lbase[b] = c ? (b * SLOTSZ + atomicAdd(&bcnt[b], c)) : 0;
        }
        __syncthreads();
        for (int b = t; b < 1024; b += 256) lcnt[b] = 0;
        __syncthreads();

        // Rank into LDS stage ordered by bucket.
        #pragma unroll
        for (int i = 0; i < 16; i++) {
            if (bk[i] >= 0) {
                int r = atomicAdd(&lcnt[bk[i]], 1);
                int pos = lexcl[bk[i]] + r;
                stage[pos] = make_int2(val[i], __float_as_int(w[i]));
                bkid[pos] = (unsigned short)bk[i];
            }
        }
        __syncthreads();

        // Linear sweep; slot-overflow guard (drop past CAP; p ~ 1e-26).
        for (int i = t; i < ctot; i += 256) {
            int b = bkid[i];
            int dest = lbase[b] + (i - lexcl[b]);
            if (dest < b * SLOTSZ + CAP) bucketed[dest] = stage[i];
        }
    }
}

// ---------------------------------------------------------------------------
// PlaceGather: one block per bucket. Phase 1: hist slot records -> scan ->
// rank into LDS stage2 (counting sort; rank pass re-reads L2-warm slots).
// Phase 2: gather from stage2 (quad-split inner loop), write agg rows
// (exactly the region this bucket's slots occupied), fused BN partials.
// 512 threads = 8 waves x 16 nodes.
// ---------------------------------------------------------------------------
__global__ __launch_bounds__(512) void placegather_kernel(const int* __restrict__ bcnt,
                                                          const int2* __restrict__ bucketed,
                                                          const unsigned short* __restrict__ support,
                                                          float* __restrict__ agg,
                                                          float* __restrict__ sums) {
    __shared__ int2 stage2[CAP];       // 20 KB (sorted bucket records)
    __shared__ int hcnt[128];
    __shared__ int sv[128];
    __shared__ int hexcl[129];
    __shared__ float red[2][8][64];    // 4 KB
    const int t = threadIdx.x;
    const int lane = t & 63;
    const int wv = t >> 6;
    const int q = lane >> 4;       // edge quarter
    const int fl = lane & 15;      // feature slot: features [4fl, 4fl+4)
    const int b = blockIdx.x;
    int nrec = bcnt[b];
    if (nrec > CAP) nrec = CAP;    // consistent with bucket guard

    if (t < 128) hcnt[t] = 0;
    __syncthreads();

    // Phase 1a: histogram local rows (lr masked: garbage-slot defense).
    for (int i = t; i < nrec; i += 512) {
        int2 rec = bucketed[b * SLOTSZ + i];
        atomicAdd(&hcnt[(rec.x >> 17) & 127], 1);
    }
    __syncthreads();

    // Phase 1b: scan 128 counts -> exclusive offsets.
    int v0 = (t < 128) ? hcnt[t] : 0;
    if (t < 128) sv[t] = v0;
    __syncthreads();
    #pragma unroll
    for (int off = 1; off < 128; off <<= 1) {
        int u = (t < 128 && t >= off) ? sv[t - off] : 0;
        __syncthreads();
        if (t < 128) sv[t] += u;
        __syncthreads();
    }
    if (t < 128) {
        int excl = sv[t] - v0;
        hexcl[t] = excl;
        hcnt[t] = excl;            // running cursor
        if (t == 127) hexcl[128] = sv[127];
    }
    __syncthreads();

    // Phase 1c: rank-scatter into sorted LDS (re-read slots, L2-warm).
    for (int i = t; i < nrec; i += 512) {
        int2 rec = bucketed[b * SLOTSZ + i];
        int lr = (rec.x >> 17) & 127;
        int pos = atomicAdd(&hcnt[lr], 1);
        stage2[pos] = make_int2(rec.x & 0x1FFFF, rec.y);
    }
    __syncthreads();

    // Phase 2: gather. Wave wv handles local rows [wv*16, wv*16+16).
    float s0 = 0.f, s1 = 0.f, s2 = 0.f, s3 = 0.f;
    float z0 = 0.f, z1 = 0.f, z2 = 0.f, z3 = 0.f;

    for (int i = wv * 16; i < wv * 16 + 16; i++) {
        const int jb = hexcl[i];
        const int je = hexcl[i + 1];
        float a0 = 0.f, a1 = 0.f, a2 = 0.f, a3 = 0.f;

        for (int base = jb; base < je; base += 16) {
            int2  mm[4];
            float ww[4];
            uint2 vv[4];
            #pragma unroll
            for (int g = 0; g < 4; g++) {
                int idx = base + (g << 2) + q;
                int ci = (idx < je) ? idx : je - 1;   // je > jb in this loop
                mm[g] = stage2[ci];
                ww[g] = (idx < je) ? __uint_as_float(mm[g].y) : 0.0f;
            }
            #pragma unroll
            for (int g = 0; g < 4; g++) {
                vv[g] = *(const uint2*)(support + (((size_t)(unsigned)mm[g].x) << 6) + (fl << 2));
            }
            #pragma unroll
            for (int g = 0; g < 4; g++) {
                a0 = fmaf(ww[g], __uint_as_float(vv[g].x << 16), a0);
                a1 = fmaf(ww[g], __uint_as_float(vv[g].x & 0xFFFF0000u), a1);
                a2 = fmaf(ww[g], __uint_as_float(vv[g].y << 16), a2);
                a3 = fmaf(ww[g], __uint_as_float(vv[g].y & 0xFFFF0000u), a3);
            }
        }

        // Combine the 4 quarters.
        a0 += __shfl_xor(a0, 16); a0 += __shfl_xor(a0, 32);
        a1 += __shfl_xor(a1, 16); a1 += __shfl_xor(a1, 32);
        a2 += __shfl_xor(a2, 16); a2 += __shfl_xor(a2, 32);
        a3 += __shfl_xor(a3, 16); a3 += __shfl_xor(a3, 32);

        int r = (b << BSHIFT) + i;
        if (lane < 16 && r < N_NODES) {
            float4 o = make_float4(a0, a1, a2, a3);
            *(float4*)&agg[(size_t)r * NHID + (fl << 2)] = o;
            s0 += a0; s1 += a1; s2 += a2; s3 += a3;
            z0 = fmaf(a0, a0, z0); z1 = fmaf(a1, a1, z1);
            z2 = fmaf(a2, a2, z2); z3 = fmaf(a3, a3, z3);
        }
    }

    if (lane < 16) {
        red[0][wv][(fl << 2) + 0] = s0;
        red[0][wv][(fl << 2) + 1] = s1;
        red[0][wv][(fl << 2) + 2] = s2;
        red[0][wv][(fl << 2) + 3] = s3;
        red[1][wv][(fl << 2) + 0] = z0;
        red[1][wv][(fl << 2) + 1] = z1;
        red[1][wv][(fl << 2) + 2] = z2;
        red[1][wv][(fl << 2) + 3] = z3;
    }
    __syncthreads();
    if (t < 64) {
        float acc = 0.f;
        #pragma unroll
        for (int k = 0; k < 8; k++) acc += red[0][k][t];
        atomicAdd(&sums[t], acc);
    } else if (t < 128) {
        int f = t - 64;
        float acc = 0.f;
        #pragma unroll
        for (int k = 0; k < 8; k++) acc += red[1][k][f];
        atomicAdd(&sums[64 + f], acc);
    }
}

// ---------------------------------------------------------------------------
// Threefry-2x32, 20 rounds, key=(0,42). Hand-verified vs JAX test vector.
// ---------------------------------------------------------------------------
__device__ __forceinline__ uint32_t rotl32(uint32_t x, int d) {
    return (x << d) | (x >> (32 - d));
}

__device__ __forceinline__ uint32_t threefry_bits(uint32_t i) {
    const uint32_t k0 = 0u, k1 = 42u;
    const uint32_t k2 = k0 ^ k1 ^ 0x1BD11BDAu;
    uint32_t x0 = 0u, x1 = i;
    x0 += k0; x1 += k1;
    x0 += x1; x1 = rotl32(x1, 13) ^ x0;
    x0 += x1; x1 = rotl32(x1, 15) ^ x0;
    x0 += x1; x1 = rotl32(x1, 26) ^ x0;
    x0 += x1; x1 = rotl32(x1, 6)  ^ x0;
    x0 += k1; x1 += k2 + 1u;
    x0 += x1; x1 = rotl32(x1, 17) ^ x0;
    x0 += x1; x1 = rotl32(x1, 29) ^ x0;
    x0 += x1; x1 = rotl32(x1, 16) ^ x0;
    x0 += x1; x1 = rotl32(x1, 24) ^ x0;
    x0 += k2; x1 += k0 + 2u;
    x0 += x1; x1 = rotl32(x1, 13) ^ x0;
    x0 += x1; x1 = rotl32(x1, 15) ^ x0;
    x0 += x1; x1 = rotl32(x1, 26) ^ x0;
    x0 += x1; x1 = rotl32(x1, 6)  ^ x0;
    x0 += k0; x1 += k1 + 3u;
    x0 += x1; x1 = rotl32(x1, 17) ^ x0;
    x0 += x1; x1 = rotl32(x1, 29) ^ x0;
    x0 += x1; x1 = rotl32(x1, 16) ^ x0;
    x0 += x1; x1 = rotl32(x1, 24) ^ x0;
    x0 += k1; x1 += k2 + 4u;
    x0 += x1; x1 = rotl32(x1, 13) ^ x0;
    x0 += x1; x1 = rotl32(x1, 15) ^ x0;
    x0 += x1; x1 = rotl32(x1, 26) ^ x0;
    x0 += x1; x1 = rotl32(x1, 6)  ^ x0;
    x0 += k2; x1 += k0 + 5u;
    return x0 ^ x1;
}

// ---------------------------------------------------------------------------
// Apply (R19): float4 per thread. BN affine + ReLU + dropout; finalize fused.
// ---------------------------------------------------------------------------
__global__ __launch_bounds__(256) void apply_kernel(const float* __restrict__ agg,
                                                    const float* __restrict__ sums,
                                                    const float* __restrict__ gamma,
                                                    const float* __restrict__ beta,
                                                    float* __restrict__ out) {
    const int i0 = (blockIdx.x * 256 + threadIdx.x) * 4;
    if (i0 >= N_ELEMS) return;
    const int f0 = i0 & 63;
    const float inv_n = 1.0f / (float)N_NODES;

    float4 a = *(const float4*)&agg[i0];
    float4 o;
    #pragma unroll
    for (int k = 0; k < 4; k++) {
        int f = f0 + k;
        float mean = sums[f] * inv_n;
        float var = sums[64 + f] * inv_n - mean * mean;
        float sc = gamma[f] * rsqrtf(var + 1e-5f);
        float sh = beta[f] - mean * sc;
        float av = (k == 0) ? a.x : (k == 1) ? a.y : (k == 2) ? a.z : a.w;
        float v = fmaxf(fmaf(av, sc, sh), 0.0f);
        uint32_t bits = threefry_bits((uint32_t)(i0 + k));
        float u = __uint_as_float((bits >> 9) | 0x3F800000u) - 1.0f;
        float r = (u < 0.7f) ? v * (1.0f / 0.7f) : 0.0f;
        if (k == 0) o.x = r; else if (k == 1) o.y = r; else if (k == 2) o.z = r; else o.w = r;
    }
    *(float4*)&out[i0] = o;
}

// ---------------------------------------------------------------------------
extern "C" void kernel_launch(void* const* d_in, const int* in_sizes, int n_in,
                              void* d_out, int out_size, void* d_ws, size_t ws_size,
                              hipStream_t stream) {
    const float* x     = (const float*)d_in[0];
    const int*   row   = (const int*)d_in[1];
    const int*   col   = (const int*)d_in[2];
    const float* ew    = (const float*)d_in[3];
    const float* W     = (const float*)d_in[4];
    const float* gamma = (const float*)d_in[6];
    const float* beta  = (const float*)d_in[7];
    float* out = (float*)d_out;

    float* sums       = (float*)d_ws;                      // 128 f32
    int*   bcnt       = (int*)(sums + 128);                // 1024 i32 (782 used)
    float* agg        = (float*)(bcnt + 1024);             // 25.62 MB (NBUCK*SLOTSZ*8)
    unsigned short* support = (unsigned short*)out;        // 6.4M bf16, in d_out
    int2*  bucketed   = (int2*)agg;                        // slotted, stride SLOTSZ

    // zero sums + bcnt (contiguous)
    hipMemsetAsync(d_ws, 0, (size_t)(128 + 1024) * 4, stream);

    gemm_bucket_kernel<<<GB_TOTAL, 256, GB_LDS, stream>>>(x, W, support,
                                                          row, col, ew, bcnt, bucketed);
    placegather_kernel<<<NBUCK, 512, 0, stream>>>(bcnt, bucketed, support, agg, sums);
    apply_kernel<<<(N_ELEMS / 4 + 255) / 256, 256, 0, stream>>>(agg, sums, gamma, beta, out);
}

// Round 12
// 263.778 us; speedup vs baseline: 1.3168x; 1.0095x over previous
//
#include <hip/hip_runtime.h>
#include <stdint.h>

#define N_NODES 100000
#define N_EDGES 1600000
#define NFEAT 256
#define NHID 64
#define N_ELEMS (N_NODES * NHID)   // 6,400,000

// Slotted row-buckets of 128 rows.
#define BSHIFT 7
#define NBUCK 782                  // ceil(100000/128)
#define CHUNK 2048                 // R20: edges per bucket block (was 4096)
#define NBBLK ((N_EDGES + CHUNK - 1) / CHUNK)   // 782
#define CAP 2560                   // records staged/sorted; mean 2048 +11sigma
#define SLOTSZ 4096                // slot stride (records) = 32KB = agg rows of bucket

// R20: gemm+bucket fused, role-interleaved 2:1 (bid%3==2 = bucket).
#define GB_TOTAL 2346              // 1564 gemm-slots (1563 used) + 782 bucket
#define GB_LDS 34816               // max(gemm 33.8KB, bucket 32KB) -> 4 blocks/CU

// Config (validated R6/R7): inputs f32, output f32, dropout = JAX partitionable
// threefry (key=(0,42), counter (0,i), bits = o0^o1).
//
// R19 post-mortem: fusion landed (273.9 -> 266.3) but gemm_bucket = 68us at
//   Occupancy 24% -- the 52KB bucket-role LDS capped ALL blocks (incl. 1563
//   gemm blocks needing 33.8KB) at 3 blocks/CU; VALUBusy 12% / MfmaUtil 1.8%
//   / HBM 17% = latency-bound at low occupancy.
// R20: CHUNK 4096->2048. Bucket LDS 52->32KB <= gemm 33.8KB -> alloc 34KB ->
//   4 blocks/CU (occupancy ceiling 37.5->50%). 782 bucket blocks, 2:1
//   interleave (bid%3==2), finer tail balance. Run shrink 5.2->2.6 rec:
//   write-amp was 1.25x, worst +6MB (~1us) vs multi-us latency win.
// Pipeline: memset -> gemm_bucket -> placegather -> apply.
//
// ws layout:
//   sums[128] f32 | bcnt[1024] i32 | agg[NBUCK*SLOTSZ*8 B = 25.62MB]
// support[6.4M] bf16 staged in d_out (dead before apply overwrites).
// bucketed aliases agg with per-bucket 32KB slots (SLOTSZ records).

typedef __attribute__((ext_vector_type(8))) short bf16x8;
typedef __attribute__((ext_vector_type(4))) float f32x4;

__device__ __forceinline__ unsigned short f2bf(float f) {
    uint32_t u = __float_as_uint(f);
    u += 0x7FFFu + ((u >> 16) & 1u);   // RNE
    return (unsigned short)(u >> 16);
}
__device__ __forceinline__ float bf2f(unsigned short u) {
    return __uint_as_float(((uint32_t)u) << 16);
}

// ---------------------------------------------------------------------------
// Fused GEMM | Bucket (R20). Role by blockIdx: bid%3==2 -> bucket block
// (bucket_id = bid/3, 782 total); else gemm block (gemm_id = (bid/3)*2 +
// bid%3, 0..1563; 1563 used). Dynamic LDS 34KB, per-role layout.
//
// GEMM: support[N x 64] = x[N x 256] @ W[256 x 64], bf16 out. W conversion
// fused (64KB, L2-hot). No A staging: lane loads own 32B of x per kstep.
// Bucket: LDS counting-reorder scatter into slotted buckets; contiguous runs.
// ---------------------------------------------------------------------------
__global__ __launch_bounds__(256) void gemm_bucket_kernel(const float* __restrict__ x,
                                                          const float* __restrict__ W,
                                                          unsigned short* __restrict__ support,
                                                          const int* __restrict__ row,
                                                          const int* __restrict__ col,
                                                          const float* __restrict__ ew,
                                                          int* __restrict__ bcnt,
                                                          int2* __restrict__ bucketed) {
    extern __shared__ char smem[];
    const int t = threadIdx.x;
    const int bid = blockIdx.x;

    if ((bid % 3) != 2) {
        // ---------------- GEMM role ----------------
        const int gemm_id = (bid / 3) * 2 + (bid % 3);
        const int row0 = gemm_id * 64;
        if (row0 >= N_NODES) return;

        unsigned short (*Bt)[264] = (unsigned short (*)[264])smem;  // 33.8 KB

        #pragma unroll
        for (int i = 0; i < 64; i++) {
            int idx = i * 256 + t;
            Bt[idx & 63][idx >> 6] = f2bf(W[idx]);
        }
        __syncthreads();

        const int lane = t & 63;
        const int w = t >> 6;
        const int m = lane & 15;
        const int q = lane >> 4;
        const int growA = row0 + w * 16 + m;
        const int lrow = (growA < N_NODES) ? growA : N_NODES - 1;
        const float* xr = x + (size_t)lrow * NFEAT;

        f32x4 acc0 = {0.f, 0.f, 0.f, 0.f};
        f32x4 acc1 = acc0, acc2 = acc0, acc3 = acc0;

        #pragma unroll
        for (int ks = 0; ks < NFEAT; ks += 32) {
            float4 xa = *(const float4*)&xr[ks + q * 8];
            float4 xb = *(const float4*)&xr[ks + q * 8 + 4];
            ushort4 ua, ub;
            ua.x = f2bf(xa.x); ua.y = f2bf(xa.y); ua.z = f2bf(xa.z); ua.w = f2bf(xa.w);
            ub.x = f2bf(xb.x); ub.y = f2bf(xb.y); ub.z = f2bf(xb.z); ub.w = f2bf(xb.w);
            union { ushort4 u4[2]; bf16x8 v8; } cv;
            cv.u4[0] = ua; cv.u4[1] = ub;
            bf16x8 af = cv.v8;

            bf16x8 b0 = *(const bf16x8*)&Bt[ 0 + m][ks + q * 8];
            bf16x8 b1 = *(const bf16x8*)&Bt[16 + m][ks + q * 8];
            bf16x8 b2 = *(const bf16x8*)&Bt[32 + m][ks + q * 8];
            bf16x8 b3 = *(const bf16x8*)&Bt[48 + m][ks + q * 8];
            acc0 = __builtin_amdgcn_mfma_f32_16x16x32_bf16(af, b0, acc0, 0, 0, 0);
            acc1 = __builtin_amdgcn_mfma_f32_16x16x32_bf16(af, b1, acc1, 0, 0, 0);
            acc2 = __builtin_amdgcn_mfma_f32_16x16x32_bf16(af, b2, acc2, 0, 0, 0);
            acc3 = __builtin_amdgcn_mfma_f32_16x16x32_bf16(af, b3, acc3, 0, 0, 0);
        }

        #pragma unroll
        for (int reg = 0; reg < 4; reg++) {
            int grow = row0 + w * 16 + q * 4 + reg;
            if (grow < N_NODES) {
                support[(size_t)grow * NHID +  0 + m] = f2bf(acc0[reg]);
                support[(size_t)grow * NHID + 16 + m] = f2bf(acc1[reg]);
                support[(size_t)grow * NHID + 32 + m] = f2bf(acc2[reg]);
                support[(size_t)grow * NHID + 48 + m] = f2bf(acc3[reg]);
            }
        }
    } else {
        // ---------------- Bucket role ----------------
        const int bblk = bid / 3;                              // 0..781
        int2* stage = (int2*)smem;                             // 16 KB
        unsigned short* bkid = (unsigned short*)(smem + 16384); // 4 KB
        int* lcnt  = (int*)(smem + 20480);                     // 4 KB
        int* lexcl = (int*)(smem + 24576);                     // 4 KB
        int* lbase = (int*)(smem + 28672);                     // 4 KB
        int* p     = lbase;                                    // overlays lbase

        for (int b = t; b < 1024; b += 256) lcnt[b] = 0;
        __syncthreads();

        const int e0 = bblk * CHUNK;
        const int ctot = (e0 + CHUNK <= N_EDGES) ? CHUNK : (N_EDGES - e0);
        int bk[8];
        int val[8];
        float w[8];
        #pragma unroll
        for (int i = 0; i < 8; i++) {
            int e = e0 + i * 256 + t;
            if (e < N_EDGES && i * 256 + t < ctot) {
                int r = row[e];
                int c = col[e];
                w[i] = ew[e];
                bk[i] = r >> BSHIFT;
                val[i] = ((r & ((1 << BSHIFT) - 1)) << 17) | c;
                atomicAdd(&lcnt[bk[i]], 1);
            } else {
                bk[i] = -1;
            }
        }
        __syncthreads();

        // Block-level exclusive scan of 1024 bucket counts (4 per thread).
        int s0 = lcnt[t * 4 + 0], s1 = lcnt[t * 4 + 1];
        int s2 = lcnt[t * 4 + 2], s3 = lcnt[t * 4 + 3];
        int tsum = s0 + s1 + s2 + s3;
        p[t] = tsum;
        __syncthreads();
        #pragma unroll
        for (int off = 1; off < 256; off <<= 1) {
            int u = (t >= off) ? p[t - off] : 0;
            __syncthreads();
            p[t] += u;
            __syncthreads();
        }
        int pe = p[t] - tsum;
        __syncthreads();   // p reads done before lbase overwrites
        lexcl[t * 4 + 0] = pe;
        lexcl[t * 4 + 1] = pe + s0;
        lexcl[t * 4 + 2] = pe + s0 + s1;
        lexcl[t * 4 + 3] = pe + s0 + s1 + s2;

        // Reserve slot runs; reset lcnt for ranking.
        for (int b = t; b < NBUCK; b += 256) {
            int c = lcnt[b];
            lbase[b] = c ? (b * SLOTSZ + atomicAdd(&bcnt[b], c)) : 0;
        }
        __syncthreads();
        for (int b = t; b < 1024; b += 256) lcnt[b] = 0;
        __syncthreads();

        // Rank into LDS stage ordered by bucket.
        #pragma unroll
        for (int i = 0; i < 8; i++) {
            if (bk[i] >= 0) {
                int r = atomicAdd(&lcnt[bk[i]], 1);
                int pos = lexcl[bk[i]] + r;
                stage[pos] = make_int2(val[i], __float_as_int(w[i]));
                bkid[pos] = (unsigned short)bk[i];
            }
        }
        __syncthreads();

        // Linear sweep; slot-overflow guard (drop past CAP; p ~ 1e-26).
        for (int i = t; i < ctot; i += 256) {
            int b = bkid[i];
            int dest = lbase[b] + (i - lexcl[b]);
            if (dest < b * SLOTSZ + CAP) bucketed[dest] = stage[i];
        }
    }
}

// ---------------------------------------------------------------------------
// PlaceGather: one block per bucket. Phase 1: hist slot records -> scan ->
// rank into LDS stage2 (counting sort; rank pass re-reads L2-warm slots).
// Phase 2: gather from stage2 (quad-split inner loop), write agg rows
// (exactly the region this bucket's slots occupied), fused BN partials.
// 512 threads = 8 waves x 16 nodes.
// ---------------------------------------------------------------------------
__global__ __launch_bounds__(512) void placegather_kernel(const int* __restrict__ bcnt,
                                                          const int2* __restrict__ bucketed,
                                                          const unsigned short* __restrict__ support,
                                                          float* __restrict__ agg,
                                                          float* __restrict__ sums) {
    __shared__ int2 stage2[CAP];       // 20 KB (sorted bucket records)
    __shared__ int hcnt[128];
    __shared__ int sv[128];
    __shared__ int hexcl[129];
    __shared__ float red[2][8][64];    // 4 KB
    const int t = threadIdx.x;
    const int lane = t & 63;
    const int wv = t >> 6;
    const int q = lane >> 4;       // edge quarter
    const int fl = lane & 15;      // feature slot: features [4fl, 4fl+4)
    const int b = blockIdx.x;
    int nrec = bcnt[b];
    if (nrec > CAP) nrec = CAP;    // consistent with bucket guard

    if (t < 128) hcnt[t] = 0;
    __syncthreads();

    // Phase 1a: histogram local rows (lr masked: garbage-slot defense).
    for (int i = t; i < nrec; i += 512) {
        int2 rec = bucketed[b * SLOTSZ + i];
        atomicAdd(&hcnt[(rec.x >> 17) & 127], 1);
    }
    __syncthreads();

    // Phase 1b: scan 128 counts -> exclusive offsets.
    int v0 = (t < 128) ? hcnt[t] : 0;
    if (t < 128) sv[t] = v0;
    __syncthreads();
    #pragma unroll
    for (int off = 1; off < 128; off <<= 1) {
        int u = (t < 128 && t >= off) ? sv[t - off] : 0;
        __syncthreads();
        if (t < 128) sv[t] += u;
        __syncthreads();
    }
    if (t < 128) {
        int excl = sv[t] - v0;
        hexcl[t] = excl;
        hcnt[t] = excl;            // running cursor
        if (t == 127) hexcl[128] = sv[127];
    }
    __syncthreads();

    // Phase 1c: rank-scatter into sorted LDS (re-read slots, L2-warm).
    for (int i = t; i < nrec; i += 512) {
        int2 rec = bucketed[b * SLOTSZ + i];
        int lr = (rec.x >> 17) & 127;
        int pos = atomicAdd(&hcnt[lr], 1);
        stage2[pos] = make_int2(rec.x & 0x1FFFF, rec.y);
    }
    __syncthreads();

    // Phase 2: gather. Wave wv handles local rows [wv*16, wv*16+16).
    float s0 = 0.f, s1 = 0.f, s2 = 0.f, s3 = 0.f;
    float z0 = 0.f, z1 = 0.f, z2 = 0.f, z3 = 0.f;

    for (int i = wv * 16; i < wv * 16 + 16; i++) {
        const int jb = hexcl[i];
        const int je = hexcl[i + 1];
        float a0 = 0.f, a1 = 0.f, a2 = 0.f, a3 = 0.f;

        for (int base = jb; base < je; base += 16) {
            int2  mm[4];
            float ww[4];
            uint2 vv[4];
            #pragma unroll
            for (int g = 0; g < 4; g++) {
                int idx = base + (g << 2) + q;
                int ci = (idx < je) ? idx : je - 1;   // je > jb in this loop
                mm[g] = stage2[ci];
                ww[g] = (idx < je) ? __uint_as_float(mm[g].y) : 0.0f;
            }
            #pragma unroll
            for (int g = 0; g < 4; g++) {
                vv[g] = *(const uint2*)(support + (((size_t)(unsigned)mm[g].x) << 6) + (fl << 2));
            }
            #pragma unroll
            for (int g = 0; g < 4; g++) {
                a0 = fmaf(ww[g], __uint_as_float(vv[g].x << 16), a0);
                a1 = fmaf(ww[g], __uint_as_float(vv[g].x & 0xFFFF0000u), a1);
                a2 = fmaf(ww[g], __uint_as_float(vv[g].y << 16), a2);
                a3 = fmaf(ww[g], __uint_as_float(vv[g].y & 0xFFFF0000u), a3);
            }
        }

        // Combine the 4 quarters.
        a0 += __shfl_xor(a0, 16); a0 += __shfl_xor(a0, 32);
        a1 += __shfl_xor(a1, 16); a1 += __shfl_xor(a1, 32);
        a2 += __shfl_xor(a2, 16); a2 += __shfl_xor(a2, 32);
        a3 += __shfl_xor(a3, 16); a3 += __shfl_xor(a3, 32);

        int r = (b << BSHIFT) + i;
        if (lane < 16 && r < N_NODES) {
            float4 o = make_float4(a0, a1, a2, a3);
            *(float4*)&agg[(size_t)r * NHID + (fl << 2)] = o;
            s0 += a0; s1 += a1; s2 += a2; s3 += a3;
            z0 = fmaf(a0, a0, z0); z1 = fmaf(a1, a1, z1);
            z2 = fmaf(a2, a2, z2); z3 = fmaf(a3, a3, z3);
        }
    }

    if (lane < 16) {
        red[0][wv][(fl << 2) + 0] = s0;
        red[0][wv][(fl << 2) + 1] = s1;
        red[0][wv][(fl << 2) + 2] = s2;
        red[0][wv][(fl << 2) + 3] = s3;
        red[1][wv][(fl << 2) + 0] = z0;
        red[1][wv][(fl << 2) + 1] = z1;
        red[1][wv][(fl << 2) + 2] = z2;
        red[1][wv][(fl << 2) + 3] = z3;
    }
    __syncthreads();
    if (t < 64) {
        float acc = 0.f;
        #pragma unroll
        for (int k = 0; k < 8; k++) acc += red[0][k][t];
        atomicAdd(&sums[t], acc);
    } else if (t < 128) {
        int f = t - 64;
        float acc = 0.f;
        #pragma unroll
        for (int k = 0; k < 8; k++) acc += red[1][k][f];
        atomicAdd(&sums[64 + f], acc);
    }
}

// ---------------------------------------------------------------------------
// Threefry-2x32, 20 rounds, key=(0,42). Hand-verified vs JAX test vector.
// ---------------------------------------------------------------------------
__device__ __forceinline__ uint32_t rotl32(uint32_t x, int d) {
    return (x << d) | (x >> (32 - d));
}

__device__ __forceinline__ uint32_t threefry_bits(uint32_t i) {
    const uint32_t k0 = 0u, k1 = 42u;
    const uint32_t k2 = k0 ^ k1 ^ 0x1BD11BDAu;
    uint32_t x0 = 0u, x1 = i;
    x0 += k0; x1 += k1;
    x0 += x1; x1 = rotl32(x1, 13) ^ x0;
    x0 += x1; x1 = rotl32(x1, 15) ^ x0;
    x0 += x1; x1 = rotl32(x1, 26) ^ x0;
    x0 += x1; x1 = rotl32(x1, 6)  ^ x0;
    x0 += k1; x1 += k2 + 1u;
    x0 += x1; x1 = rotl32(x1, 17) ^ x0;
    x0 += x1; x1 = rotl32(x1, 29) ^ x0;
    x0 += x1; x1 = rotl32(x1, 16) ^ x0;
    x0 += x1; x1 = rotl32(x1, 24) ^ x0;
    x0 += k2; x1 += k0 + 2u;
    x0 += x1; x1 = rotl32(x1, 13) ^ x0;
    x0 += x1; x1 = rotl32(x1, 15) ^ x0;
    x0 += x1; x1 = rotl32(x1, 26) ^ x0;
    x0 += x1; x1 = rotl32(x1, 6)  ^ x0;
    x0 += k0; x1 += k1 + 3u;
    x0 += x1; x1 = rotl32(x1, 17) ^ x0;
    x0 += x1; x1 = rotl32(x1, 29) ^ x0;
    x0 += x1; x1 = rotl32(x1, 16) ^ x0;
    x0 += x1; x1 = rotl32(x1, 24) ^ x0;
    x0 += k1; x1 += k2 + 4u;
    x0 += x1; x1 = rotl32(x1, 13) ^ x0;
    x0 += x1; x1 = rotl32(x1, 15) ^ x0;
    x0 += x1; x1 = rotl32(x1, 26) ^ x0;
    x0 += x1; x1 = rotl32(x1, 6)  ^ x0;
    x0 += k2; x1 += k0 + 5u;
    return x0 ^ x1;
}

// ---------------------------------------------------------------------------
// Apply: float4 per thread. BN affine + ReLU + dropout; finalize fused.
// ---------------------------------------------------------------------------
__global__ __launch_bounds__(256) void apply_kernel(const float* __restrict__ agg,
                                                    const float* __restrict__ sums,
                                                    const float* __restrict__ gamma,
                                                    const float* __restrict__ beta,
                                                    float* __restrict__ out) {
    const int i0 = (blockIdx.x * 256 + threadIdx.x) * 4;
    if (i0 >= N_ELEMS) return;
    const int f0 = i0 & 63;
    const float inv_n = 1.0f / (float)N_NODES;

    float4 a = *(const float4*)&agg[i0];
    float4 o;
    #pragma unroll
    for (int k = 0; k < 4; k++) {
        int f = f0 + k;
        float mean = sums[f] * inv_n;
        float var = sums[64 + f] * inv_n - mean * mean;
        float sc = gamma[f] * rsqrtf(var + 1e-5f);
        float sh = beta[f] - mean * sc;
        float av = (k == 0) ? a.x : (k == 1) ? a.y : (k == 2) ? a.z : a.w;
        float v = fmaxf(fmaf(av, sc, sh), 0.0f);
        uint32_t bits = threefry_bits((uint32_t)(i0 + k));
        float u = __uint_as_float((bits >> 9) | 0x3F800000u) - 1.0f;
        float r = (u < 0.7f) ? v * (1.0f / 0.7f) : 0.0f;
        if (k == 0) o.x = r; else if (k == 1) o.y = r; else if (k == 2) o.z = r; else o.w = r;
    }
    *(float4*)&out[i0] = o;
}

// ---------------------------------------------------------------------------
extern "C" void kernel_launch(void* const* d_in, const int* in_sizes, int n_in,
                              void* d_out, int out_size, void* d_ws, size_t ws_size,
                              hipStream_t stream) {
    const float* x     = (const float*)d_in[0];
    const int*   row   = (const int*)d_in[1];
    const int*   col   = (const int*)d_in[2];
    const float* ew    = (const float*)d_in[3];
    const float* W     = (const float*)d_in[4];
    const float* gamma = (const float*)d_in[6];
    const float* beta  = (const float*)d_in[7];
    float* out = (float*)d_out;

    float* sums       = (float*)d_ws;                      // 128 f32
    int*   bcnt       = (int*)(sums + 128);                // 1024 i32 (782 used)
    float* agg        = (float*)(bcnt + 1024);             // 25.62 MB (NBUCK*SLOTSZ*8)
    unsigned short* support = (unsigned short*)out;        // 6.4M bf16, in d_out
    int2*  bucketed   = (int2*)agg;                        // slotted, stride SLOTSZ

    // zero sums + bcnt (contiguous)
    hipMemsetAsync(d_ws, 0, (size_t)(128 + 1024) * 4, stream);

    gemm_bucket_kernel<<<GB_TOTAL, 256, GB_LDS, stream>>>(x, W, support,
                                                          row, col, ew, bcnt, bucketed);
    placegather_kernel<<<NBUCK, 512, 0, stream>>>(bcnt, bucketed, support, agg, sums);
    apply_kernel<<<(N_ELEMS / 4 + 255) / 256, 256, 0, stream>>>(agg, sums, gamma, beta, out);
}